// Round 4
// baseline (3984.148 us; speedup 1.0000x reference)
//
#include <hip/hip_runtime.h>
#include <hip/hip_cooperative_groups.h>

namespace cg = cooperative_groups;

// ---------------- workspace layout (float offsets) ----------------
#define OFF_X     0          // x_flat [32][46656]
#define OFF_CUR1  1492992    // [32][1000]
#define OFF_MEM1  1524992
#define OFF_MEM2  1556992
#define OFF_MEM3  1588992
#define OFF_SPK1  1620992
#define OFF_SPK1B 1652992
#define OFF_SPK2  1684992
#define OFF_SPK3  1716992
#define OFF_K     1780992
#define OFF_V     1812992
#define OFF_MEMR  1844992    // [32][100]
#define OFF_SPKR  1848192    // [32][100]
#define OFF_MEMO  1851392    // [32]
#define OFF_PATT  1851424    // [32][8]
#define OFF_CNT   1851680    // [5][4]
#define OFF_OACC  1851700    // [32]
#define OFF_SC    1851732    // total, reg
#define OFF_PART  1851744    // gemm1 partials [nchunk][32][1000]
// step-loop split-K partials (region reused after gemm1_reduce)
#define OFF_PG    OFF_PART               // [25][32][1000]
#define OFF_PKK   (OFF_PART + 800000)    // [25][32][1000]
#define OFF_PVV   (OFF_PART + 1600000)   // [25][32][1000]

static constexpr float kBETA  = 0.8f;
static constexpr float kTHR   = 0.5f;
static constexpr float kBETAR = 0.95f;
static constexpr float kTHRR  = 1.0f;
static constexpr float kLM    = 0.0058f;

// ---------------- init: zero all persistent state ----------------
__global__ void k_init(float* ws) {
    int idx = blockIdx.x * 256 + threadIdx.x;
    if (idx < 96000) {
        ws[OFF_MEM1 + idx] = 0.f;                 // mem1, mem2, mem3
    } else {
        int j = idx - 96000;
        if (j < 6744) ws[OFF_MEMR + j] = 0.f;     // mem_r..sc region
    }
}

// ---------------- patch embed ----------------
__global__ __launch_bounds__(64) void k_patch(
    const float* __restrict__ data, const float* __restrict__ Wpe,
    const float* __restrict__ bpe, const float* __restrict__ pos,
    float* __restrict__ xf)
{
    int bp = blockIdx.x;
    int b = bp / 729, p = bp % 729;
    int pr = p / 27, pc = p % 27;
    int tid = threadIdx.x;
    __shared__ float patch[256];
    const float* db = data + (size_t)b * 50176;
    for (int c = tid; c < 256; c += 64) {
        int ph = c >> 4, pw = c & 15;
        patch[c] = db[(pr * 8 + ph) * 224 + pc * 8 + pw];
    }
    __syncthreads();
    float acc = bpe[tid] + pos[p * 64 + tid];
    for (int c = 0; c < 256; ++c)
        acc = fmaf(patch[c], Wpe[c * 64 + tid], acc);
    xf[(size_t)b * 46656 + p * 64 + tid] = acc;
}

// ---------------- big GEMM partials (unchanged, proven) ----------------
__global__ __launch_bounds__(256) void k_gemm1_part(
    const float* __restrict__ xf, const float* __restrict__ W1,
    float* __restrict__ part, int tpc)
{
    int chunk = blockIdx.x;
    int hg = blockIdx.y;
    int bg = blockIdx.z;
    int t0 = chunk * tpc;
    int t1 = t0 + tpc; if (t1 > 729) t1 = 729;
    int tid = threadIdx.x;
    __shared__ float xs[1024];
    float acc[16][2];
    #pragma unroll
    for (int b = 0; b < 16; ++b) { acc[b][0] = 0.f; acc[b][1] = 0.f; }

    const size_t bbase = (size_t)(bg * 16) * 46656;
    const int hbase = hg * 500;
    for (int tt = t0; tt < t1; ++tt) {
        int i0 = tt * 64;
        __syncthreads();
        for (int l = tid; l < 1024; l += 256)
            xs[l] = xf[bbase + (size_t)(l >> 6) * 46656 + i0 + (l & 63)];
        __syncthreads();
        for (int ii4 = 0; ii4 < 16; ++ii4) {
            int i = i0 + ii4 * 4;
            float w0[2], w1v[2], w2[2], w3[2];
            #pragma unroll
            for (int j = 0; j < 2; ++j) {
                int hh = tid + j * 256;
                bool ok = hh < 500;
                const float* col = W1 + (size_t)i * 1000 + hbase + (ok ? hh : 0);
                w0[j]  = ok ? col[0]    : 0.f;
                w1v[j] = ok ? col[1000] : 0.f;
                w2[j]  = ok ? col[2000] : 0.f;
                w3[j]  = ok ? col[3000] : 0.f;
            }
            #pragma unroll
            for (int b = 0; b < 16; ++b) {
                float4 xv = *reinterpret_cast<const float4*>(&xs[b * 64 + ii4 * 4]);
                #pragma unroll
                for (int j = 0; j < 2; ++j) {
                    float a = acc[b][j];
                    a = fmaf(xv.x, w0[j],  a);
                    a = fmaf(xv.y, w1v[j], a);
                    a = fmaf(xv.z, w2[j],  a);
                    a = fmaf(xv.w, w3[j],  a);
                    acc[b][j] = a;
                }
            }
        }
    }
    float* pc = part + (size_t)chunk * 32000;
    for (int b = 0; b < 16; ++b)
        #pragma unroll
        for (int j = 0; j < 2; ++j) {
            int hh = tid + j * 256;
            if (hh < 500) pc[(bg * 16 + b) * 1000 + hbase + hh] = acc[b][j];
        }
}

__global__ void k_gemm1_reduce(const float* __restrict__ part,
                               const float* __restrict__ b1,
                               float* __restrict__ cur1, int nchunk)
{
    int idx = blockIdx.x * 256 + threadIdx.x;
    if (idx >= 32000) return;
    int h = idx % 1000;
    float a = b1[h];
    for (int c = 0; c < nchunk; ++c) a += part[(size_t)c * 32000 + idx];
    cur1[idx] = a;
}

// ================= cooperative mega-kernel for the 5-step loop =================
struct MA {
    const float *cur1, *W2, *b2, *W3, *b3, *WR, *bR, *Vw, *Vb;
    const float *Wq, *bq, *Wk, *bk, *Wv, *bv, *Wo, *bo;
    float *mem1, *mem2, *mem3, *spk1, *spk1b, *spk2, *spk3;
    float *kb, *vb2, *memr, *spkr, *memo, *patt, *cnt, *oacc, *sc, *dout;
    float *pg, *pkk, *pvv;
};

__device__ __forceinline__ void final_body(const MA& A, int t, int tid)
{
    // executed by wave 0 (tid < 64) of one block
    float s = 0.f;
    if (tid < 32) {
        float a = A.bo[0];
        for (int it = 0; it < 8; ++it) a += A.patt[tid * 8 + it];
        float m = A.memo[tid];
        float r = (m - kTHR > 0.f) ? kTHR : 0.f;
        float mn = __fsub_rn(__fadd_rn(__fmul_rn(kBETA, m), a), r);
        A.memo[tid] = mn;
        s = (mn - kTHR > 0.f) ? 1.f : 0.f;
        float oa = A.oacc[tid] + s;
        A.oacc[tid] = oa;
        if (t == 4) A.dout[tid] = oa / 5.0f;
    }
    unsigned long long msk = __ballot(s > 0.5f);
    float co = (float)__popcll(msk);
    const float* cnt = A.cnt + t * 4;
    if (tid == 0) {
        float total = A.sc[0];
        float prev = total;
        total = __fadd_rn(total, __fdiv_rn(cnt[0], 32000.f));
        total = __fadd_rn(total, __fdiv_rn(cnt[1], 32000.f));
        total = __fadd_rn(total, __fdiv_rn(cnt[2], 3200.f));
        total = __fadd_rn(total, __fdiv_rn(co, 32.f));
        float reg = A.sc[1];
        reg = __fadd_rn(reg, __fmul_rn(kLM, total));
        if (t > 0) reg = __fadd_rn(reg, __fmul_rn(kLM, fabsf(__fsub_rn(total, prev))));
        A.sc[0] = total; A.sc[1] = reg;
        if (t == 4) A.dout[32] = reg / 5.0f;
    }
}

// split-K spike-GEMM partial unit (R2's proven k_gsp body): W read ONCE total,
// all 32 batches accumulated in registers. 1280 floats of lds scratch.
__device__ __forceinline__ void gsp_unit(
    const float* __restrict__ Ain, const float* __restrict__ W,
    float* __restrict__ pg, int unit, int tid, float* al)
{
    int hs = unit / 25, kc = unit % 25;
    int j0 = kc * 40;
    for (int l = tid; l < 1280; l += 512)
        al[l] = Ain[(size_t)(l & 31) * 1000 + j0 + (l >> 5)];
    __syncthreads();
    if (tid < 125) {
        int h = hs * 125 + tid;
        float acc[32];
        #pragma unroll
        for (int b = 0; b < 32; ++b) acc[b] = 0.f;
        const float* Wp = W + (size_t)j0 * 1000 + h;
        #pragma unroll 2
        for (int jj = 0; jj < 40; ++jj) {
            float w = Wp[(size_t)jj * 1000];
            const float4* a4 = reinterpret_cast<const float4*>(&al[jj * 32]);
            #pragma unroll
            for (int q = 0; q < 8; ++q) {
                float4 av = a4[q];
                acc[q * 4 + 0] = fmaf(av.x, w, acc[q * 4 + 0]);
                acc[q * 4 + 1] = fmaf(av.y, w, acc[q * 4 + 1]);
                acc[q * 4 + 2] = fmaf(av.z, w, acc[q * 4 + 2]);
                acc[q * 4 + 3] = fmaf(av.w, w, acc[q * 4 + 3]);
            }
        }
        float* pp = pg + (size_t)kc * 32000 + h;
        #pragma unroll
        for (int b = 0; b < 32; ++b) pp[(size_t)b * 1000] = acc[b];
    }
}

__device__ __forceinline__ void gsp_unit_kv(
    const float* __restrict__ Ain, const float* __restrict__ Wk,
    const float* __restrict__ Wv, float* __restrict__ pk, float* __restrict__ pv,
    int unit, int tid, float* al)
{
    int hs = unit / 25, kc = unit % 25;
    int j0 = kc * 40;
    for (int l = tid; l < 1280; l += 512)
        al[l] = Ain[(size_t)(l & 31) * 1000 + j0 + (l >> 5)];
    __syncthreads();
    if (tid < 125) {
        int h = hs * 125 + tid;
        float ak[32], av2[32];
        #pragma unroll
        for (int b = 0; b < 32; ++b) { ak[b] = 0.f; av2[b] = 0.f; }
        const float* wkp = Wk + (size_t)j0 * 1000 + h;
        const float* wvp = Wv + (size_t)j0 * 1000 + h;
        #pragma unroll 2
        for (int jj = 0; jj < 40; ++jj) {
            float wk = wkp[(size_t)jj * 1000];
            float wv = wvp[(size_t)jj * 1000];
            const float4* a4 = reinterpret_cast<const float4*>(&al[jj * 32]);
            #pragma unroll
            for (int q = 0; q < 8; ++q) {
                float4 av = a4[q];
                ak[q * 4 + 0] = fmaf(av.x, wk, ak[q * 4 + 0]);
                ak[q * 4 + 1] = fmaf(av.y, wk, ak[q * 4 + 1]);
                ak[q * 4 + 2] = fmaf(av.z, wk, ak[q * 4 + 2]);
                ak[q * 4 + 3] = fmaf(av.w, wk, ak[q * 4 + 3]);
                av2[q * 4 + 0] = fmaf(av.x, wv, av2[q * 4 + 0]);
                av2[q * 4 + 1] = fmaf(av.y, wv, av2[q * 4 + 1]);
                av2[q * 4 + 2] = fmaf(av.z, wv, av2[q * 4 + 2]);
                av2[q * 4 + 3] = fmaf(av.w, wv, av2[q * 4 + 3]);
            }
        }
        float* ppk = pk + (size_t)kc * 32000 + h;
        float* ppv = pv + (size_t)kc * 32000 + h;
        #pragma unroll
        for (int b = 0; b < 32; ++b) {
            ppk[(size_t)b * 1000] = ak[b];
            ppv[(size_t)b * 1000] = av2[b];
        }
    }
}

__global__ __launch_bounds__(512, 2) void k_mega(MA A)
{
    cg::grid_group grid = cg::this_grid();
    const int gid = blockIdx.x, tid = threadIdx.x;
    __shared__ float lds[3200];

#define GSYNC() do { __threadfence(); grid.sync(); } while (0)

    for (int t = 0; t < 5; ++t) {
        float* cnt = A.cnt + t * 4;

        // ---- P0: stepA double-leaky (+ final(t-1) on block 255) ----
        {
            int idx = gid * 512 + tid;
            float s1v = 0.f;
            if (idx < 32000) {
                float m = A.mem1[idx], c = A.cur1[idx];
                float r1 = (m - kTHR > 0.f) ? kTHR : 0.f;
                float ma = __fsub_rn(__fadd_rn(__fmul_rn(kBETA, m), c), r1);
                s1v = (ma - kTHR > 0.f) ? 1.f : 0.f;
                float r2 = __fmul_rn(s1v, kTHR);
                float mb = __fsub_rn(__fadd_rn(__fmul_rn(kBETA, ma), c), r2);
                A.mem1[idx] = mb;
                A.spk1[idx] = s1v;
                A.spk1b[idx] = (mb - kTHR > 0.f) ? 1.f : 0.f;
            }
            unsigned long long msk = __ballot(s1v > 0.5f);
            if ((tid & 63) == 0) {
                int p = __popcll(msk);
                if (p) atomicAdd(cnt + 0, (float)p);
            }
            if (gid == 255 && t > 0 && tid < 64) final_body(A, t - 1, tid);
        }
        GSYNC();

        // ---- P1: GEMM2 partials (units 0..199) + RLeaky (blocks 200..231) ----
        if (gid < 200) {
            gsp_unit(A.spk1b, A.W2, A.pg, gid, tid, lds);
        } else if (gid < 232) {
            int b = gid - 200;
            float* s1 = lds;           // 1000
            float* sr = lds + 1000;    // 100
            float* red = lds + 1104;   // 512
            for (int l = tid; l < 1000; l += 512) s1[l] = A.spk1[b * 1000 + l];
            if (tid < 100) sr[tid] = A.spkr[b * 100 + tid];
            __syncthreads();
            int ks = tid >> 7, hh = tid & 127;
            float p = 0.f;
            if (hh < 100) {
                const float* wp = A.WR + (size_t)(ks * 250) * 100 + hh;
                #pragma unroll 5
                for (int j = 0; j < 250; ++j)
                    p = fmaf(s1[ks * 250 + j], wp[(size_t)j * 100], p);
            }
            red[ks * 128 + hh] = p;
            __syncthreads();
            float s = 0.f;
            if (tid < 100) {
                float acc = A.bR[tid] + red[tid] + red[128 + tid] + red[256 + tid] + red[384 + tid];
                float rec = 0.f;
                for (int j = 0; j < 100; ++j) rec = fmaf(sr[j], A.Vw[j * 100 + tid], rec);
                float m = A.memr[b * 100 + tid];
                float r = (m - kTHRR > 0.f) ? kTHRR : 0.f;
                float mn = __fsub_rn(__fadd_rn(__fadd_rn(__fadd_rn(__fmul_rn(kBETAR, m), acc), rec), A.Vb[tid]), r);
                s = (mn - kTHRR > 0.f) ? 1.f : 0.f;
                A.memr[b * 100 + tid] = mn;
                A.spkr[b * 100 + tid] = s;
            }
            unsigned long long msk = __ballot(s > 0.5f);
            if ((tid & 63) == 0) {
                int p2 = __popcll(msk);
                if (p2) atomicAdd(cnt + 2, (float)p2);
            }
        }
        GSYNC();

        // ---- P2: reduce2 + leaky -> spk2 ----
        {
            int idx = gid * 512 + tid;
            if (idx < 32000) {
                int h = idx % 1000;
                float a = A.b2[h];
                for (int c = 0; c < 25; ++c) a += A.pg[(size_t)c * 32000 + idx];
                float m = A.mem2[idx];
                float r = (m - kTHR > 0.f) ? kTHR : 0.f;
                float mn = __fsub_rn(__fadd_rn(__fmul_rn(kBETA, m), a), r);
                A.mem2[idx] = mn;
                A.spk2[idx] = (mn - kTHR > 0.f) ? 1.f : 0.f;
            }
        }
        GSYNC();

        // ---- P3: GEMM3 partials ----
        if (gid < 200) gsp_unit(A.spk2, A.W3, A.pg, gid, tid, lds);
        GSYNC();

        // ---- P4: reduce3 + leaky -> spk3 (+count) ----
        {
            int idx = gid * 512 + tid;
            float s = 0.f;
            if (idx < 32000) {
                int h = idx % 1000;
                float a = A.b3[h];
                for (int c = 0; c < 25; ++c) a += A.pg[(size_t)c * 32000 + idx];
                float m = A.mem3[idx];
                float r = (m - kTHR > 0.f) ? kTHR : 0.f;
                float mn = __fsub_rn(__fadd_rn(__fmul_rn(kBETA, m), a), r);
                A.mem3[idx] = mn;
                s = (mn - kTHR > 0.f) ? 1.f : 0.f;
                A.spk3[idx] = s;
            }
            unsigned long long msk = __ballot(s > 0.5f);
            if ((tid & 63) == 0) {
                int p = __popcll(msk);
                if (p) atomicAdd(cnt + 1, (float)p);
            }
        }
        GSYNC();

        // ---- P5: KV partials ----
        if (gid < 200) gsp_unit_kv(A.spk3, A.Wk, A.Wv, A.pkk, A.pvv, gid, tid, lds);
        GSYNC();

        // ---- P6: reduce KV ----
        {
            int idx = gid * 512 + tid;
            if (idx < 32000) {
                int h = idx % 1000;
                float ak = A.bk[h], av = A.bv[h];
                for (int c = 0; c < 25; ++c) {
                    ak += A.pkk[(size_t)c * 32000 + idx];
                    av += A.pvv[(size_t)c * 32000 + idx];
                }
                A.kb[idx] = ak;
                A.vb2[idx] = av;
            }
        }
        GSYNC();

        // ---- P7: attention with fused q-GEMM ----
        {
            int b = gid >> 3, it = gid & 7;
            float* kk = lds;             // 1000
            float* vv = lds + 1000;      // 1000
            float* sr = lds + 2000;      // 100
            float* red = lds + 2112;     // 512
            float pmax = -3.4e38f, pmin = 3.4e38f;
            if (tid < 100) sr[tid] = A.spkr[b * 100 + tid];
            for (int j = tid; j < 1000; j += 512) {
                float kj = A.kb[b * 1000 + j];
                kk[j] = kj;
                vv[j] = A.vb2[b * 1000 + j];
                pmax = fmaxf(pmax, kj);
                pmin = fminf(pmin, kj);
            }
            red[tid] = pmax;
            __syncthreads();
            for (int s2 = 256; s2 > 0; s2 >>= 1) {
                if (tid < s2) red[tid] = fmaxf(red[tid], red[tid + s2]);
                __syncthreads();
            }
            float kmax = red[0];
            __syncthreads();
            red[tid] = pmin;
            __syncthreads();
            for (int s2 = 256; s2 > 0; s2 >>= 1) {
                if (tid < s2) red[tid] = fminf(red[tid], red[tid + s2]);
                __syncthreads();
            }
            float kmin = red[0];
            __syncthreads();
            float pw = 0.f;
            if (tid < 125) {
                int i = it * 125 + tid;
                float qi = A.bq[i];
                for (int j = 0; j < 100; ++j) qi = fmaf(sr[j], A.Wq[j * 1000 + i], qi);
                float qs = qi / 31.62277660168379f;   // sqrt(1000)
                float m = (qs >= 0.f) ? qs * kmax : qs * kmin;
                float den = 0.f, num = 0.f;
                for (int j = 0; j < 1000; ++j) {
                    float e = __expf(fmaf(qs, kk[j], -m));
                    den += e;
                    num = fmaf(e, vv[j], num);
                }
                pw = (num / den) * A.Wo[i];
            }
            red[tid] = pw;
            __syncthreads();
            for (int s2 = 256; s2 > 0; s2 >>= 1) {
                if (tid < s2) red[tid] += red[tid + s2];
                __syncthreads();
            }
            if (tid == 0) A.patt[b * 8 + it] = red[0];
        }
        GSYNC();
    }

    // final(4)
    if (gid == 0 && tid < 64) final_body(A, 4, tid);
#undef GSYNC
}

// ---------------- host ----------------
extern "C" void kernel_launch(void* const* d_in, const int* in_sizes, int n_in,
                              void* d_out, int out_size, void* d_ws, size_t ws_size,
                              hipStream_t stream)
{
    const float* data = (const float*)d_in[0];
    const float* Wpe  = (const float*)d_in[1];
    const float* bpe  = (const float*)d_in[2];
    const float* pos  = (const float*)d_in[3];
    const float* W1   = (const float*)d_in[4];
    const float* b1   = (const float*)d_in[5];
    const float* W2   = (const float*)d_in[6];
    const float* b2   = (const float*)d_in[7];
    const float* W3   = (const float*)d_in[8];
    const float* b3   = (const float*)d_in[9];
    const float* WR   = (const float*)d_in[10];
    const float* bR   = (const float*)d_in[11];
    const float* Vw   = (const float*)d_in[12];
    const float* Vb   = (const float*)d_in[13];
    const float* Wq   = (const float*)d_in[14];
    const float* bq   = (const float*)d_in[15];
    const float* Wk   = (const float*)d_in[16];
    const float* bk   = (const float*)d_in[17];
    const float* Wv   = (const float*)d_in[18];
    const float* bv   = (const float*)d_in[19];
    const float* Wo   = (const float*)d_in[20];
    const float* bo   = (const float*)d_in[21];

    float* ws = (float*)d_ws;
    float* dout = (float*)d_out;

    float* xf    = ws + OFF_X;
    float* cur1  = ws + OFF_CUR1;
    float* part  = ws + OFF_PART;

    // chunk count for the big GEMM
    size_t ws_f = ws_size / 4;
    size_t avail = (ws_f > OFF_PART) ? (ws_f - OFF_PART) : 0;
    long nchunk_l = (long)(avail / 32000);
    int nchunk = (nchunk_l > 365) ? 365 : (int)nchunk_l;
    if (nchunk < 1) nchunk = 1;
    int tpc = (729 + nchunk - 1) / nchunk;
    nchunk = (729 + tpc - 1) / tpc;

    k_init<<<402, 256, 0, stream>>>(ws);
    k_patch<<<23328, 64, 0, stream>>>(data, Wpe, bpe, pos, xf);
    k_gemm1_part<<<dim3(nchunk, 2, 2), 256, 0, stream>>>(xf, W1, part, tpc);
    k_gemm1_reduce<<<125, 256, 0, stream>>>(part, b1, cur1, nchunk);

    MA ma;
    ma.cur1 = cur1;
    ma.W2 = W2; ma.b2 = b2; ma.W3 = W3; ma.b3 = b3;
    ma.WR = WR; ma.bR = bR; ma.Vw = Vw; ma.Vb = Vb;
    ma.Wq = Wq; ma.bq = bq; ma.Wk = Wk; ma.bk = bk;
    ma.Wv = Wv; ma.bv = bv; ma.Wo = Wo; ma.bo = bo;
    ma.mem1 = ws + OFF_MEM1; ma.mem2 = ws + OFF_MEM2; ma.mem3 = ws + OFF_MEM3;
    ma.spk1 = ws + OFF_SPK1; ma.spk1b = ws + OFF_SPK1B;
    ma.spk2 = ws + OFF_SPK2; ma.spk3 = ws + OFF_SPK3;
    ma.kb = ws + OFF_K; ma.vb2 = ws + OFF_V;
    ma.memr = ws + OFF_MEMR; ma.spkr = ws + OFF_SPKR;
    ma.memo = ws + OFF_MEMO; ma.patt = ws + OFF_PATT;
    ma.cnt = ws + OFF_CNT; ma.oacc = ws + OFF_OACC; ma.sc = ws + OFF_SC;
    ma.dout = dout;
    ma.pg = ws + OFF_PG; ma.pkk = ws + OFF_PKK; ma.pvv = ws + OFF_PVV;

    void* kp[] = { (void*)&ma };
    hipLaunchCooperativeKernel(k_mega, dim3(256), dim3(512), kp, 0, stream);

    (void)in_sizes; (void)n_in; (void)out_size;
}

// Round 5
// 886.375 us; speedup vs baseline: 4.4949x; 4.4949x over previous
//
#include <hip/hip_runtime.h>

// ---------------- workspace layout (float offsets) ----------------
#define OFF_X     0          // x_flat [32][46656]
#define OFF_CUR1  1492992    // [32][1000]
#define OFF_MEM1  1524992    // [32][1000]
#define OFF_MEM2  1556992    // [32][1000]  (slot A)
#define OFF_MEM3  1588992    // [32][1000]  (slot A)
#define OFF_SPK1B 1652992    // [32][1000]
#define OFF_MEMR  1844992    // [32][100]
#define OFF_SPKR  1848192    // [32][100]
#define OFF_MEMO  1851392    // [32]
#define OFF_PATT  1851424    // [32][8]
#define OFF_CNT   1851680    // [5][4] spike counters
#define OFF_OACC  1851700    // [32]
#define OFF_SC    1851732    // total, reg
#define OFF_TICK  1851736    // [5] uint ticket counters (one per step)
#define OFF_PART  1851744    // gemm1 partials [nchunk][32][1000]
// step-loop buffers (overlay the gemm1 partial region after it's consumed)
#define OFF_PG2   OFF_PART               // [25][32][1000]
#define OFF_PG3   (OFF_PART + 800000)    // [25][32][1000]
#define OFF_PKK   (OFF_PART + 1600000)   // [25][32][1000]
#define OFF_PVV   (OFF_PART + 2400000)   // [25][32][1000]
#define OFF_M2B   (OFF_PART + 3200000)   // [32][1000] mem2 slot B
#define OFF_M3B   (OFF_PART + 3232000)   // [32][1000] mem3 slot B

static constexpr float kBETA  = 0.8f;
static constexpr float kTHR   = 0.5f;
static constexpr float kBETAR = 0.95f;
static constexpr float kTHRR  = 1.0f;
static constexpr float kLM    = 0.0058f;

// ---------------- init: zero all persistent state ----------------
__global__ void k_init(float* ws) {
    int idx = blockIdx.x * 256 + threadIdx.x;
    if (idx < 96000) {
        ws[OFF_MEM1 + idx] = 0.f;                 // mem1, mem2, mem3 (slot A)
    } else {
        int j = idx - 96000;
        if (j < 6752) ws[OFF_MEMR + j] = 0.f;     // mem_r..sc + tick counters
    }
}

// ---------------- patch embed ----------------
__global__ __launch_bounds__(64) void k_patch(
    const float* __restrict__ data, const float* __restrict__ Wpe,
    const float* __restrict__ bpe, const float* __restrict__ pos,
    float* __restrict__ xf)
{
    int bp = blockIdx.x;
    int b = bp / 729, p = bp % 729;
    int pr = p / 27, pc = p % 27;
    int tid = threadIdx.x;
    __shared__ float patch[256];
    const float* db = data + (size_t)b * 50176;
    for (int c = tid; c < 256; c += 64) {
        int ph = c >> 4, pw = c & 15;
        patch[c] = db[(pr * 8 + ph) * 224 + pc * 8 + pw];
    }
    __syncthreads();
    float acc = bpe[tid] + pos[p * 64 + tid];
    for (int c = 0; c < 256; ++c)
        acc = fmaf(patch[c], Wpe[c * 64 + tid], acc);
    xf[(size_t)b * 46656 + p * 64 + tid] = acc;
}

// ---------------- big GEMM partials (proven R3 h-split) ----------------
__global__ __launch_bounds__(256) void k_gemm1_part(
    const float* __restrict__ xf, const float* __restrict__ W1,
    float* __restrict__ part, int tpc)
{
    int chunk = blockIdx.x;
    int hg = blockIdx.y;
    int bg = blockIdx.z;
    int t0 = chunk * tpc;
    int t1 = t0 + tpc; if (t1 > 729) t1 = 729;
    int tid = threadIdx.x;
    __shared__ float xs[1024];
    float acc[16][2];
    #pragma unroll
    for (int b = 0; b < 16; ++b) { acc[b][0] = 0.f; acc[b][1] = 0.f; }

    const size_t bbase = (size_t)(bg * 16) * 46656;
    const int hbase = hg * 500;
    for (int tt = t0; tt < t1; ++tt) {
        int i0 = tt * 64;
        __syncthreads();
        for (int l = tid; l < 1024; l += 256)
            xs[l] = xf[bbase + (size_t)(l >> 6) * 46656 + i0 + (l & 63)];
        __syncthreads();
        for (int ii4 = 0; ii4 < 16; ++ii4) {
            int i = i0 + ii4 * 4;
            float w0[2], w1v[2], w2[2], w3[2];
            #pragma unroll
            for (int j = 0; j < 2; ++j) {
                int hh = tid + j * 256;
                bool ok = hh < 500;
                const float* col = W1 + (size_t)i * 1000 + hbase + (ok ? hh : 0);
                w0[j]  = ok ? col[0]    : 0.f;
                w1v[j] = ok ? col[1000] : 0.f;
                w2[j]  = ok ? col[2000] : 0.f;
                w3[j]  = ok ? col[3000] : 0.f;
            }
            #pragma unroll
            for (int b = 0; b < 16; ++b) {
                float4 xv = *reinterpret_cast<const float4*>(&xs[b * 64 + ii4 * 4]);
                #pragma unroll
                for (int j = 0; j < 2; ++j) {
                    float a = acc[b][j];
                    a = fmaf(xv.x, w0[j],  a);
                    a = fmaf(xv.y, w1v[j], a);
                    a = fmaf(xv.z, w2[j],  a);
                    a = fmaf(xv.w, w3[j],  a);
                    acc[b][j] = a;
                }
            }
        }
    }
    float* pc = part + (size_t)chunk * 32000;
    for (int b = 0; b < 16; ++b)
        #pragma unroll
        for (int j = 0; j < 2; ++j) {
            int hh = tid + j * 256;
            if (hh < 500) pc[(bg * 16 + b) * 1000 + hbase + hh] = acc[b][j];
        }
}

__global__ void k_gemm1_reduce(const float* __restrict__ part,
                               const float* __restrict__ b1,
                               float* __restrict__ cur1, int nchunk)
{
    int idx = blockIdx.x * 256 + threadIdx.x;
    if (idx >= 32000) return;
    int h = idx % 1000;
    float a = b1[h];
    for (int c = 0; c < nchunk; ++c) a += part[(size_t)c * 32000 + idx];
    cur1[idx] = a;
}

// ---------------- fused stepA (double leaky) + RLeaky (R3, proven) ----------------
__global__ __launch_bounds__(256) void k_stepR(
    const float* __restrict__ cur1, float* __restrict__ mem1,
    float* __restrict__ spk1b,
    const float* __restrict__ WR, const float* __restrict__ bR,
    const float* __restrict__ Vw, const float* __restrict__ Vb,
    float* __restrict__ mem_r, float* __restrict__ spk_r,
    float* cnt0, float* cnt2)
{
    int b = blockIdx.x;
    int tid = threadIdx.x;
    __shared__ float s1[1000];
    __shared__ float sr[100];
    __shared__ float red2[2][128];
    __shared__ float csum[4];

    float localc = 0.f;
    if (tid < 250) {
        int base = b * 1000 + tid * 4;
        float4 m4 = *reinterpret_cast<const float4*>(&mem1[base]);
        float4 c4 = *reinterpret_cast<const float4*>(&cur1[base]);
        float mm[4] = {m4.x, m4.y, m4.z, m4.w};
        float cc[4] = {c4.x, c4.y, c4.z, c4.w};
        float mb[4], sb[4];
        #pragma unroll
        for (int q = 0; q < 4; ++q) {
            float m = mm[q], c = cc[q];
            float r1 = (m - kTHR > 0.f) ? kTHR : 0.f;
            float ma = __fsub_rn(__fadd_rn(__fmul_rn(kBETA, m), c), r1);
            float s  = (ma - kTHR > 0.f) ? 1.f : 0.f;
            float r2 = __fmul_rn(s, kTHR);
            float mv = __fsub_rn(__fadd_rn(__fmul_rn(kBETA, ma), c), r2);
            sb[q] = (mv - kTHR > 0.f) ? 1.f : 0.f;
            mb[q] = mv;
            s1[tid * 4 + q] = s;
            localc += s;
        }
        *reinterpret_cast<float4*>(&mem1[base])  = make_float4(mb[0], mb[1], mb[2], mb[3]);
        *reinterpret_cast<float4*>(&spk1b[base]) = make_float4(sb[0], sb[1], sb[2], sb[3]);
    }
    if (tid < 100) sr[tid] = spk_r[b * 100 + tid];
    for (int off = 32; off; off >>= 1) localc += __shfl_down(localc, off, 64);
    if ((tid & 63) == 0) csum[tid >> 6] = localc;
    __syncthreads();
    if (tid == 0) atomicAdd(cnt0, csum[0] + csum[1] + csum[2] + csum[3]);

    int ks = tid >> 7, hh = tid & 127;
    float p = 0.f;
    if (hh < 100) {
        const float* wp = WR + (size_t)(ks * 500) * 100 + hh;
        int j0 = ks * 500;
        #pragma unroll 4
        for (int j = 0; j < 500; ++j) p = fmaf(s1[j0 + j], wp[(size_t)j * 100], p);
    }
    red2[ks][hh] = p;
    __syncthreads();
    float s = 0.f;
    if (tid < 100) {
        float acc = bR[tid] + red2[0][tid] + red2[1][tid];
        float rec = 0.f;
        for (int j = 0; j < 100; ++j) rec = fmaf(sr[j], Vw[j * 100 + tid], rec);
        float m = mem_r[b * 100 + tid];
        float r = (m - kTHRR > 0.f) ? kTHRR : 0.f;
        float mn = __fsub_rn(__fadd_rn(__fadd_rn(__fadd_rn(__fmul_rn(kBETAR, m), acc), rec), Vb[tid]), r);
        s = (mn - kTHRR > 0.f) ? 1.f : 0.f;
        mem_r[b * 100 + tid] = mn;
        spk_r[b * 100 + tid] = s;
    }
    unsigned long long msk = __ballot(s > 0.5f);
    if ((tid & 63) == 0) atomicAdd(cnt2, (float)__popcll(msk));
}

// ---------------- split-K spike-GEMM partial (R2, proven): W read ONCE ----------------
__global__ __launch_bounds__(128) void k_gsp(
    const float* __restrict__ A, const float* __restrict__ W,
    float* __restrict__ part)
{
    int hb = blockIdx.x, kc = blockIdx.y, tid = threadIdx.x;
    int j0 = kc * 40;
    __shared__ __align__(16) float al[1280];
    for (int l = tid; l < 1280; l += 128)
        al[l] = A[(size_t)(l & 31) * 1000 + j0 + (l >> 5)];
    __syncthreads();
    if (tid >= 125) return;
    int h = hb * 125 + tid;
    float acc[32];
    #pragma unroll
    for (int b = 0; b < 32; ++b) acc[b] = 0.f;
    const float* Wp = W + (size_t)j0 * 1000 + h;
    #pragma unroll 2
    for (int jj = 0; jj < 40; ++jj) {
        float w = Wp[(size_t)jj * 1000];
        const float4* a4 = reinterpret_cast<const float4*>(&al[jj * 32]);
        #pragma unroll
        for (int q = 0; q < 8; ++q) {
            float4 av = a4[q];
            acc[q * 4 + 0] = fmaf(av.x, w, acc[q * 4 + 0]);
            acc[q * 4 + 1] = fmaf(av.y, w, acc[q * 4 + 1]);
            acc[q * 4 + 2] = fmaf(av.z, w, acc[q * 4 + 2]);
            acc[q * 4 + 3] = fmaf(av.w, w, acc[q * 4 + 3]);
        }
    }
    float* pp = part + (size_t)kc * 32000 + h;
    #pragma unroll
    for (int b = 0; b < 32; ++b) pp[(size_t)b * 1000] = acc[b];
}

// ---------------- reduce(prev partials)+leaky staged in LDS, then GEMM ----------------
// grid (8 hs, 25 kc), 256 thr. mem ping-pong: all blocks read mem_old; hs==0 writes mem_new.
// Reduce order (bias + c=0..24) is bit-identical to the old k_gred.
template <bool COUNT>
__global__ __launch_bounds__(256) void k_gspred(
    const float* __restrict__ pin, const float* __restrict__ bias,
    const float* __restrict__ mem_old, float* __restrict__ mem_new,
    const float* __restrict__ W, float* __restrict__ pout, float* cnt)
{
    int hs = blockIdx.x, kc = blockIdx.y, tid = threadIdx.x;
    int j0 = kc * 40;
    __shared__ __align__(16) float al[1280];
    __shared__ float csum[4];
    float localc = 0.f;
    for (int e = tid; e < 1280; e += 256) {
        int jj = e % 40, b = e / 40;
        int idx = b * 1000 + j0 + jj;
        float a = bias[j0 + jj];
        #pragma unroll 5
        for (int c = 0; c < 25; ++c) a += pin[(size_t)c * 32000 + idx];
        float m = mem_old[idx];
        float r = (m - kTHR > 0.f) ? kTHR : 0.f;
        float mn = __fsub_rn(__fadd_rn(__fmul_rn(kBETA, m), a), r);
        float s = (mn - kTHR > 0.f) ? 1.f : 0.f;
        al[jj * 32 + b] = s;
        if (hs == 0) { mem_new[idx] = mn; localc += s; }
    }
    if (COUNT) {
        for (int off = 32; off; off >>= 1) localc += __shfl_down(localc, off, 64);
        if ((tid & 63) == 0) csum[tid >> 6] = localc;
    }
    __syncthreads();
    if (COUNT && tid == 0 && hs == 0) {
        float tot = csum[0] + csum[1] + csum[2] + csum[3];
        if (tot != 0.f) atomicAdd(cnt, tot);
    }
    if (tid < 125) {
        int h = hs * 125 + tid;
        float acc[32];
        #pragma unroll
        for (int b = 0; b < 32; ++b) acc[b] = 0.f;
        const float* Wp = W + (size_t)j0 * 1000 + h;
        #pragma unroll 2
        for (int jj = 0; jj < 40; ++jj) {
            float w = Wp[(size_t)jj * 1000];
            const float4* a4 = reinterpret_cast<const float4*>(&al[jj * 32]);
            #pragma unroll
            for (int q = 0; q < 8; ++q) {
                float4 av = a4[q];
                acc[q * 4 + 0] = fmaf(av.x, w, acc[q * 4 + 0]);
                acc[q * 4 + 1] = fmaf(av.y, w, acc[q * 4 + 1]);
                acc[q * 4 + 2] = fmaf(av.z, w, acc[q * 4 + 2]);
                acc[q * 4 + 3] = fmaf(av.w, w, acc[q * 4 + 3]);
            }
        }
        float* pp = pout + (size_t)kc * 32000 + h;
        #pragma unroll
        for (int b = 0; b < 32; ++b) pp[(size_t)b * 1000] = acc[b];
    }
}

// dual-weight variant: layer-3 reduce+leaky(+count) staged, then K and V partials
__global__ __launch_bounds__(256) void k_gspred_kv(
    const float* __restrict__ pin, const float* __restrict__ bias,
    const float* __restrict__ mem_old, float* __restrict__ mem_new,
    const float* __restrict__ Wk, const float* __restrict__ Wv,
    float* __restrict__ pk, float* __restrict__ pv, float* cnt)
{
    int hs = blockIdx.x, kc = blockIdx.y, tid = threadIdx.x;
    int j0 = kc * 40;
    __shared__ __align__(16) float al[1280];
    __shared__ float csum[4];
    float localc = 0.f;
    for (int e = tid; e < 1280; e += 256) {
        int jj = e % 40, b = e / 40;
        int idx = b * 1000 + j0 + jj;
        float a = bias[j0 + jj];
        #pragma unroll 5
        for (int c = 0; c < 25; ++c) a += pin[(size_t)c * 32000 + idx];
        float m = mem_old[idx];
        float r = (m - kTHR > 0.f) ? kTHR : 0.f;
        float mn = __fsub_rn(__fadd_rn(__fmul_rn(kBETA, m), a), r);
        float s = (mn - kTHR > 0.f) ? 1.f : 0.f;
        al[jj * 32 + b] = s;
        if (hs == 0) { mem_new[idx] = mn; localc += s; }
    }
    for (int off = 32; off; off >>= 1) localc += __shfl_down(localc, off, 64);
    if ((tid & 63) == 0) csum[tid >> 6] = localc;
    __syncthreads();
    if (tid == 0 && hs == 0) {
        float tot = csum[0] + csum[1] + csum[2] + csum[3];
        if (tot != 0.f) atomicAdd(cnt, tot);
    }
    if (tid < 125) {
        int h = hs * 125 + tid;
        float ak[32], av2[32];
        #pragma unroll
        for (int b = 0; b < 32; ++b) { ak[b] = 0.f; av2[b] = 0.f; }
        const float* wkp = Wk + (size_t)j0 * 1000 + h;
        const float* wvp = Wv + (size_t)j0 * 1000 + h;
        #pragma unroll 2
        for (int jj = 0; jj < 40; ++jj) {
            float wk = wkp[(size_t)jj * 1000];
            float wv = wvp[(size_t)jj * 1000];
            const float4* a4 = reinterpret_cast<const float4*>(&al[jj * 32]);
            #pragma unroll
            for (int q = 0; q < 8; ++q) {
                float4 av = a4[q];
                ak[q * 4 + 0] = fmaf(av.x, wk, ak[q * 4 + 0]);
                ak[q * 4 + 1] = fmaf(av.y, wk, ak[q * 4 + 1]);
                ak[q * 4 + 2] = fmaf(av.z, wk, ak[q * 4 + 2]);
                ak[q * 4 + 3] = fmaf(av.w, wk, ak[q * 4 + 3]);
                av2[q * 4 + 0] = fmaf(av.x, wv, av2[q * 4 + 0]);
                av2[q * 4 + 1] = fmaf(av.y, wv, av2[q * 4 + 1]);
                av2[q * 4 + 2] = fmaf(av.z, wv, av2[q * 4 + 2]);
                av2[q * 4 + 3] = fmaf(av.w, wv, av2[q * 4 + 3]);
            }
        }
        float* ppk = pk + (size_t)kc * 32000 + h;
        float* ppv = pv + (size_t)kc * 32000 + h;
        #pragma unroll
        for (int b = 0; b < 32; ++b) {
            ppk[(size_t)b * 1000] = ak[b];
            ppv[(size_t)b * 1000] = av2[b];
        }
    }
}

// ---------------- attention: reduce K/V partials in staging + fused q-GEMM + last-block final ----------------
__global__ __launch_bounds__(256) void k_attnred(
    const float* __restrict__ pkk, const float* __restrict__ pvv,
    const float* __restrict__ bk, const float* __restrict__ bv,
    const float* __restrict__ spkr, const float* __restrict__ Wq,
    const float* __restrict__ bq, const float* __restrict__ Wo,
    const float* __restrict__ bo,
    float* __restrict__ patt, float* __restrict__ memo,
    float* __restrict__ oacc, const float* __restrict__ cnt,
    float* __restrict__ sc, float* __restrict__ dout,
    unsigned int* __restrict__ tick, int t)
{
    int it = blockIdx.x, b = blockIdx.y;
    int tid = threadIdx.x;
    __shared__ float kk[1000], vv[1000];
    __shared__ float sr[100];
    __shared__ float red[256];
    __shared__ int isLast;
    float pmax = -3.4e38f, pmin = 3.4e38f;
    if (tid < 100) sr[tid] = spkr[b * 100 + tid];
    for (int h = tid; h < 1000; h += 256) {
        int idx = b * 1000 + h;
        float ak = bk[h], av = bv[h];
        #pragma unroll 5
        for (int c = 0; c < 25; ++c) {
            ak += pkk[(size_t)c * 32000 + idx];
            av += pvv[(size_t)c * 32000 + idx];
        }
        kk[h] = ak; vv[h] = av;
        pmax = fmaxf(pmax, ak);
        pmin = fminf(pmin, ak);
    }
    red[tid] = pmax;
    __syncthreads();
    for (int s2 = 128; s2 > 0; s2 >>= 1) {
        if (tid < s2) red[tid] = fmaxf(red[tid], red[tid + s2]);
        __syncthreads();
    }
    float kmax = red[0];
    __syncthreads();
    red[tid] = pmin;
    __syncthreads();
    for (int s2 = 128; s2 > 0; s2 >>= 1) {
        if (tid < s2) red[tid] = fminf(red[tid], red[tid + s2]);
        __syncthreads();
    }
    float kmin = red[0];
    __syncthreads();
    float pw = 0.f;
    if (tid < 125) {
        int i = it * 125 + tid;
        float qi = bq[i];
        for (int j = 0; j < 100; ++j) qi = fmaf(sr[j], Wq[j * 1000 + i], qi);
        float qs = qi / 31.62277660168379f;   // sqrt(1000)
        float m = (qs >= 0.f) ? qs * kmax : qs * kmin;
        float den = 0.f, num = 0.f;
        for (int j = 0; j < 1000; ++j) {
            float e = __expf(fmaf(qs, kk[j], -m));
            den += e;
            num = fmaf(e, vv[j], num);
        }
        pw = (num / den) * Wo[i];
    }
    red[tid] = pw;
    __syncthreads();
    for (int s2 = 128; s2 > 0; s2 >>= 1) {
        if (tid < s2) red[tid] += red[tid + s2];
        __syncthreads();
    }
    if (tid == 0) patt[b * 8 + it] = red[0];
    __syncthreads();
    if (tid == 0) {
        __threadfence();
        unsigned r = atomicAdd(tick, 1u);
        isLast = (r == 255u) ? 1 : 0;
    }
    __syncthreads();
    if (isLast && tid < 64) {
        __threadfence();
        float s = 0.f;
        if (tid < 32) {
            float a = bo[0];
            for (int itx = 0; itx < 8; ++itx) a += patt[tid * 8 + itx];
            float m = memo[tid];
            float r = (m - kTHR > 0.f) ? kTHR : 0.f;
            float mn = __fsub_rn(__fadd_rn(__fmul_rn(kBETA, m), a), r);
            memo[tid] = mn;
            s = (mn - kTHR > 0.f) ? 1.f : 0.f;
            float oa = oacc[tid] + s;
            oacc[tid] = oa;
            if (t == 4) dout[tid] = oa / 5.0f;
        }
        unsigned long long msk = __ballot(s > 0.5f);
        float co = (float)__popcll(msk);
        if (tid == 0) {
            float total = sc[0];
            float prev = total;
            total = __fadd_rn(total, __fdiv_rn(cnt[0], 32000.f));
            total = __fadd_rn(total, __fdiv_rn(cnt[1], 32000.f));
            total = __fadd_rn(total, __fdiv_rn(cnt[2], 3200.f));
            total = __fadd_rn(total, __fdiv_rn(co, 32.f));
            float reg = sc[1];
            reg = __fadd_rn(reg, __fmul_rn(kLM, total));
            if (t > 0) reg = __fadd_rn(reg, __fmul_rn(kLM, fabsf(__fsub_rn(total, prev))));
            sc[0] = total; sc[1] = reg;
            if (t == 4) dout[32] = reg / 5.0f;
        }
    }
}

// ---------------- host ----------------
extern "C" void kernel_launch(void* const* d_in, const int* in_sizes, int n_in,
                              void* d_out, int out_size, void* d_ws, size_t ws_size,
                              hipStream_t stream)
{
    const float* data = (const float*)d_in[0];
    const float* Wpe  = (const float*)d_in[1];
    const float* bpe  = (const float*)d_in[2];
    const float* pos  = (const float*)d_in[3];
    const float* W1   = (const float*)d_in[4];
    const float* b1   = (const float*)d_in[5];
    const float* W2   = (const float*)d_in[6];
    const float* b2   = (const float*)d_in[7];
    const float* W3   = (const float*)d_in[8];
    const float* b3   = (const float*)d_in[9];
    const float* WR   = (const float*)d_in[10];
    const float* bR   = (const float*)d_in[11];
    const float* Vw   = (const float*)d_in[12];
    const float* Vb   = (const float*)d_in[13];
    const float* Wq   = (const float*)d_in[14];
    const float* bq   = (const float*)d_in[15];
    const float* Wk   = (const float*)d_in[16];
    const float* bk   = (const float*)d_in[17];
    const float* Wv   = (const float*)d_in[18];
    const float* bv   = (const float*)d_in[19];
    const float* Wo   = (const float*)d_in[20];
    const float* bo   = (const float*)d_in[21];

    float* ws = (float*)d_ws;
    float* dout = (float*)d_out;

    float* xf    = ws + OFF_X;
    float* cur1  = ws + OFF_CUR1;
    float* mem1  = ws + OFF_MEM1;
    float* mem2a = ws + OFF_MEM2;
    float* mem3a = ws + OFF_MEM3;
    float* spk1b = ws + OFF_SPK1B;
    float* memr  = ws + OFF_MEMR;
    float* spkr  = ws + OFF_SPKR;
    float* memo  = ws + OFF_MEMO;
    float* patt  = ws + OFF_PATT;
    float* cntb  = ws + OFF_CNT;
    float* oacc  = ws + OFF_OACC;
    float* sc    = ws + OFF_SC;
    unsigned int* tick = (unsigned int*)(ws + OFF_TICK);
    float* part  = ws + OFF_PART;
    float* pg2   = ws + OFF_PG2;
    float* pg3   = ws + OFF_PG3;
    float* pkk   = ws + OFF_PKK;
    float* pvv   = ws + OFF_PVV;
    float* mem2b = ws + OFF_M2B;
    float* mem3b = ws + OFF_M3B;

    // chunk count for the big GEMM
    size_t ws_f = ws_size / 4;
    size_t avail = (ws_f > OFF_PART) ? (ws_f - OFF_PART) : 0;
    long nchunk_l = (long)(avail / 32000);
    int nchunk = (nchunk_l > 365) ? 365 : (int)nchunk_l;
    if (nchunk < 1) nchunk = 1;
    int tpc = (729 + nchunk - 1) / nchunk;
    nchunk = (729 + tpc - 1) / tpc;

    k_init<<<402, 256, 0, stream>>>(ws);
    k_patch<<<23328, 64, 0, stream>>>(data, Wpe, bpe, pos, xf);
    k_gemm1_part<<<dim3(nchunk, 2, 2), 256, 0, stream>>>(xf, W1, part, tpc);
    k_gemm1_reduce<<<125, 256, 0, stream>>>(part, b1, cur1, nchunk);

    for (int t = 0; t < 5; ++t) {
        float* cnt = cntb + t * 4;
        float* m2o = (t & 1) ? mem2b : mem2a;
        float* m2n = (t & 1) ? mem2a : mem2b;
        float* m3o = (t & 1) ? mem3b : mem3a;
        float* m3n = (t & 1) ? mem3a : mem3b;

        // 1. double-leaky + RLeaky
        k_stepR<<<32, 256, 0, stream>>>(cur1, mem1, spk1b, WR, bR, Vw, Vb,
                                        memr, spkr, cnt + 0, cnt + 2);
        // 2. layer-2 GEMM partials: spk1b @ W2 -> pg2
        k_gsp<<<dim3(8, 25), 128, 0, stream>>>(spk1b, W2, pg2);
        // 3. reduce pg2 + leaky(mem2) staged, GEMM @ W3 -> pg3
        k_gspred<false><<<dim3(8, 25), 256, 0, stream>>>(
            pg2, b2, m2o, m2n, W3, pg3, nullptr);
        // 4. reduce pg3 + leaky(mem3)(+count) staged, GEMM @ Wk/Wv -> pkk, pvv
        k_gspred_kv<<<dim3(8, 25), 256, 0, stream>>>(
            pg3, b3, m3o, m3n, Wk, Wv, pkk, pvv, cnt + 1);
        // 5. attention: reduce K/V + fused q + softmax + last-block final
        k_attnred<<<dim3(8, 32), 256, 0, stream>>>(
            pkk, pvv, bk, bv, spkr, Wq, bq, Wo, bo,
            patt, memo, oacc, cnt, sc, dout, tick + t, t);
    }
    (void)in_sizes; (void)n_in; (void)out_size;
}

// Round 6
// 786.532 us; speedup vs baseline: 5.0655x; 1.1269x over previous
//
#include <hip/hip_runtime.h>

// ---------------- workspace layout (float offsets) ----------------
#define OFF_X     0          // x_flat [32][46656]
#define OFF_CUR1  1492992    // [32][1000]
#define OFF_MEM1  1524992    // [32][1000]
#define OFF_MEM2  1556992    // [32][1000]  (slot A)
#define OFF_MEM3  1588992    // [32][1000]  (slot A)
#define OFF_SPK1B 1652992    // [32][1000]
#define OFF_MEMR  1844992    // [32][100]
#define OFF_SPKR  1848192    // [32][100]
#define OFF_MEMO  1851392    // [32]
#define OFF_PATT  1851424    // [32][8]
#define OFF_CNT   1851680    // [5][4] spike counters
#define OFF_OACC  1851700    // [32]
#define OFF_SC    1851732    // total, reg
#define OFF_TICK  1851736    // [5] uint ticket counters (one per step)
#define OFF_PART  1851744    // gemm1 partials [nchunk<=122][32][1000]
// step-loop buffers (overlay the gemm1 partial region after it's consumed)
#define OFF_PG2   OFF_PART               // [25][32][1000]
#define OFF_PG3   (OFF_PART + 800000)    // [25][32][1000]
#define OFF_PKK   (OFF_PART + 1600000)   // [25][32][1000]
#define OFF_PVV   (OFF_PART + 2400000)   // [25][32][1000]
#define OFF_M2B   (OFF_PART + 3200000)   // [32][1000] mem2 slot B
#define OFF_M3B   (OFF_PART + 3232000)   // [32][1000] mem3 slot B

static constexpr float kBETA  = 0.8f;
static constexpr float kTHR   = 0.5f;
static constexpr float kBETAR = 0.95f;
static constexpr float kTHRR  = 1.0f;
static constexpr float kLM    = 0.0058f;

// ---------------- init: zero all persistent state ----------------
__global__ void k_init(float* ws) {
    int idx = blockIdx.x * 256 + threadIdx.x;
    if (idx < 96000) {
        ws[OFF_MEM1 + idx] = 0.f;                 // mem1, mem2, mem3 (slot A)
    } else {
        int j = idx - 96000;
        if (j < 6752) ws[OFF_MEMR + j] = 0.f;     // mem_r..sc + tick counters
    }
}

// ---------------- patch embed ----------------
__global__ __launch_bounds__(64) void k_patch(
    const float* __restrict__ data, const float* __restrict__ Wpe,
    const float* __restrict__ bpe, const float* __restrict__ pos,
    float* __restrict__ xf)
{
    int bp = blockIdx.x;
    int b = bp / 729, p = bp % 729;
    int pr = p / 27, pc = p % 27;
    int tid = threadIdx.x;
    __shared__ float patch[256];
    const float* db = data + (size_t)b * 50176;
    for (int c = tid; c < 256; c += 64) {
        int ph = c >> 4, pw = c & 15;
        patch[c] = db[(pr * 8 + ph) * 224 + pc * 8 + pw];
    }
    __syncthreads();
    float acc = bpe[tid] + pos[p * 64 + tid];
    for (int c = 0; c < 256; ++c)
        acc = fmaf(patch[c], Wpe[c * 64 + tid], acc);
    xf[(size_t)b * 46656 + p * 64 + tid] = acc;
}

// ---------------- big GEMM partials: W1 read ONCE (no batch split) ----------------
// grid (nchunk=122, 2 hg), 256 thr, acc[32][2]. Partials 15.6 MB (mostly L2).
__global__ __launch_bounds__(256) void k_gemm1_part(
    const float* __restrict__ xf, const float* __restrict__ W1,
    float* __restrict__ part, int tpc)
{
    int chunk = blockIdx.x;
    int hg = blockIdx.y;
    int t0 = chunk * tpc;
    int t1 = t0 + tpc; if (t1 > 729) t1 = 729;
    int tid = threadIdx.x;
    __shared__ float xs[2048];           // [32 b][64 i]
    float acc[32][2];
    #pragma unroll
    for (int b = 0; b < 32; ++b) { acc[b][0] = 0.f; acc[b][1] = 0.f; }

    const int hbase = hg * 500;
    for (int tt = t0; tt < t1; ++tt) {
        int i0 = tt * 64;
        __syncthreads();
        for (int l = tid; l < 2048; l += 256)
            xs[l] = xf[(size_t)(l >> 6) * 46656 + i0 + (l & 63)];
        __syncthreads();
        for (int ii4 = 0; ii4 < 16; ++ii4) {
            int i = i0 + ii4 * 4;
            float w0[2], w1v[2], w2[2], w3[2];
            #pragma unroll
            for (int j = 0; j < 2; ++j) {
                int hh = tid + j * 256;
                bool ok = hh < 500;
                const float* col = W1 + (size_t)i * 1000 + hbase + (ok ? hh : 0);
                w0[j]  = ok ? col[0]    : 0.f;
                w1v[j] = ok ? col[1000] : 0.f;
                w2[j]  = ok ? col[2000] : 0.f;
                w3[j]  = ok ? col[3000] : 0.f;
            }
            #pragma unroll
            for (int b = 0; b < 32; ++b) {
                float4 xv = *reinterpret_cast<const float4*>(&xs[b * 64 + ii4 * 4]);
                #pragma unroll
                for (int j = 0; j < 2; ++j) {
                    float a = acc[b][j];
                    a = fmaf(xv.x, w0[j],  a);
                    a = fmaf(xv.y, w1v[j], a);
                    a = fmaf(xv.z, w2[j],  a);
                    a = fmaf(xv.w, w3[j],  a);
                    acc[b][j] = a;
                }
            }
        }
    }
    float* pc = part + (size_t)chunk * 32000;
    for (int b = 0; b < 32; ++b)
        #pragma unroll
        for (int j = 0; j < 2; ++j) {
            int hh = tid + j * 256;
            if (hh < 500) pc[b * 1000 + hbase + hh] = acc[b][j];
        }
}

__global__ void k_gemm1_reduce(const float* __restrict__ part,
                               const float* __restrict__ b1,
                               float* __restrict__ cur1, int nchunk)
{
    int idx = blockIdx.x * 128 + threadIdx.x;   // 250 blocks x 128
    if (idx >= 32000) return;
    int h = idx % 1000;
    float a = b1[h];
    for (int c = 0; c < nchunk; ++c) a += part[(size_t)c * 32000 + idx];
    cur1[idx] = a;
}

// ---------------- fused stepA (double leaky) + RLeaky (proven) ----------------
__global__ __launch_bounds__(256) void k_stepR(
    const float* __restrict__ cur1, float* __restrict__ mem1,
    float* __restrict__ spk1b,
    const float* __restrict__ WR, const float* __restrict__ bR,
    const float* __restrict__ Vw, const float* __restrict__ Vb,
    float* __restrict__ mem_r, float* __restrict__ spk_r,
    float* cnt0, float* cnt2)
{
    int b = blockIdx.x;
    int tid = threadIdx.x;
    __shared__ float s1[1000];
    __shared__ float sr[100];
    __shared__ float red2[2][128];
    __shared__ float csum[4];

    float localc = 0.f;
    if (tid < 250) {
        int base = b * 1000 + tid * 4;
        float4 m4 = *reinterpret_cast<const float4*>(&mem1[base]);
        float4 c4 = *reinterpret_cast<const float4*>(&cur1[base]);
        float mm[4] = {m4.x, m4.y, m4.z, m4.w};
        float cc[4] = {c4.x, c4.y, c4.z, c4.w};
        float mb[4], sb[4];
        #pragma unroll
        for (int q = 0; q < 4; ++q) {
            float m = mm[q], c = cc[q];
            float r1 = (m - kTHR > 0.f) ? kTHR : 0.f;
            float ma = __fsub_rn(__fadd_rn(__fmul_rn(kBETA, m), c), r1);
            float s  = (ma - kTHR > 0.f) ? 1.f : 0.f;
            float r2 = __fmul_rn(s, kTHR);
            float mv = __fsub_rn(__fadd_rn(__fmul_rn(kBETA, ma), c), r2);
            sb[q] = (mv - kTHR > 0.f) ? 1.f : 0.f;
            mb[q] = mv;
            s1[tid * 4 + q] = s;
            localc += s;
        }
        *reinterpret_cast<float4*>(&mem1[base])  = make_float4(mb[0], mb[1], mb[2], mb[3]);
        *reinterpret_cast<float4*>(&spk1b[base]) = make_float4(sb[0], sb[1], sb[2], sb[3]);
    }
    if (tid < 100) sr[tid] = spk_r[b * 100 + tid];
    for (int off = 32; off; off >>= 1) localc += __shfl_down(localc, off, 64);
    if ((tid & 63) == 0) csum[tid >> 6] = localc;
    __syncthreads();
    if (tid == 0) atomicAdd(cnt0, csum[0] + csum[1] + csum[2] + csum[3]);

    int ks = tid >> 7, hh = tid & 127;
    float p = 0.f;
    if (hh < 100) {
        const float* wp = WR + (size_t)(ks * 500) * 100 + hh;
        int j0 = ks * 500;
        #pragma unroll 4
        for (int j = 0; j < 500; ++j) p = fmaf(s1[j0 + j], wp[(size_t)j * 100], p);
    }
    red2[ks][hh] = p;
    __syncthreads();
    float s = 0.f;
    if (tid < 100) {
        float acc = bR[tid] + red2[0][tid] + red2[1][tid];
        float rec = 0.f;
        for (int j = 0; j < 100; ++j) rec = fmaf(sr[j], Vw[j * 100 + tid], rec);
        float m = mem_r[b * 100 + tid];
        float r = (m - kTHRR > 0.f) ? kTHRR : 0.f;
        float mn = __fsub_rn(__fadd_rn(__fadd_rn(__fadd_rn(__fmul_rn(kBETAR, m), acc), rec), Vb[tid]), r);
        s = (mn - kTHRR > 0.f) ? 1.f : 0.f;
        mem_r[b * 100 + tid] = mn;
        spk_r[b * 100 + tid] = s;
    }
    unsigned long long msk = __ballot(s > 0.5f);
    if ((tid & 63) == 0) atomicAdd(cnt2, (float)__popcll(msk));
}

// ---------------- split-K spike-GEMM partial: 256 thr, 2-way in-block K-split ----------------
__global__ __launch_bounds__(256) void k_gsp(
    const float* __restrict__ A, const float* __restrict__ W,
    float* __restrict__ part)
{
    int hb = blockIdx.x, kc = blockIdx.y, tid = threadIdx.x;
    int j0 = kc * 40;
    __shared__ __align__(16) float al[1280];
    __shared__ float redg[32 * 128];     // [b][hh]
    for (int l = tid; l < 1280; l += 256)
        al[l] = A[(size_t)(l & 31) * 1000 + j0 + (l >> 5)];
    __syncthreads();
    int ks = tid >> 7, hh = tid & 127;
    float acc[32];
    #pragma unroll
    for (int b = 0; b < 32; ++b) acc[b] = 0.f;
    if (hh < 125) {
        int h = hb * 125 + hh;
        const float* Wp = W + (size_t)(j0 + ks * 20) * 1000 + h;
        const float4* abase = reinterpret_cast<const float4*>(&al[ks * 20 * 32]);
        #pragma unroll 2
        for (int jj = 0; jj < 20; ++jj) {
            float w = Wp[(size_t)jj * 1000];
            const float4* a4 = abase + jj * 8;
            #pragma unroll
            for (int q = 0; q < 8; ++q) {
                float4 av = a4[q];
                acc[q * 4 + 0] = fmaf(av.x, w, acc[q * 4 + 0]);
                acc[q * 4 + 1] = fmaf(av.y, w, acc[q * 4 + 1]);
                acc[q * 4 + 2] = fmaf(av.z, w, acc[q * 4 + 2]);
                acc[q * 4 + 3] = fmaf(av.w, w, acc[q * 4 + 3]);
            }
        }
    }
    if (ks == 1 && hh < 125) {
        #pragma unroll
        for (int b = 0; b < 32; ++b) redg[b * 128 + hh] = acc[b];
    }
    __syncthreads();
    if (ks == 0 && hh < 125) {
        int h = hb * 125 + hh;
        float* pp = part + (size_t)kc * 32000 + h;
        #pragma unroll
        for (int b = 0; b < 32; ++b) pp[(size_t)b * 1000] = acc[b] + redg[b * 128 + hh];
    }
}

// ---------------- reduce(prev partials)+leaky staged in LDS, then split GEMM ----------------
template <bool COUNT>
__global__ __launch_bounds__(256) void k_gspred(
    const float* __restrict__ pin, const float* __restrict__ bias,
    const float* __restrict__ mem_old, float* __restrict__ mem_new,
    const float* __restrict__ W, float* __restrict__ pout, float* cnt)
{
    int hs = blockIdx.x, kc = blockIdx.y, tid = threadIdx.x;
    int j0 = kc * 40;
    __shared__ __align__(16) float al[1280];
    __shared__ float redg[32 * 128];
    __shared__ float csum[4];
    float localc = 0.f;
    for (int e = tid; e < 1280; e += 256) {
        int jj = e % 40, b = e / 40;
        int idx = b * 1000 + j0 + jj;
        float a = bias[j0 + jj];
        #pragma unroll 5
        for (int c = 0; c < 25; ++c) a += pin[(size_t)c * 32000 + idx];
        float m = mem_old[idx];
        float r = (m - kTHR > 0.f) ? kTHR : 0.f;
        float mn = __fsub_rn(__fadd_rn(__fmul_rn(kBETA, m), a), r);
        float s = (mn - kTHR > 0.f) ? 1.f : 0.f;
        al[jj * 32 + b] = s;
        if (hs == 0) { mem_new[idx] = mn; localc += s; }
    }
    if (COUNT) {
        for (int off = 32; off; off >>= 1) localc += __shfl_down(localc, off, 64);
        if ((tid & 63) == 0) csum[tid >> 6] = localc;
    }
    __syncthreads();
    if (COUNT && tid == 0 && hs == 0) {
        float tot = csum[0] + csum[1] + csum[2] + csum[3];
        if (tot != 0.f) atomicAdd(cnt, tot);
    }
    int ks = tid >> 7, hh = tid & 127;
    float acc[32];
    #pragma unroll
    for (int b = 0; b < 32; ++b) acc[b] = 0.f;
    if (hh < 125) {
        int h = hs * 125 + hh;
        const float* Wp = W + (size_t)(j0 + ks * 20) * 1000 + h;
        const float4* abase = reinterpret_cast<const float4*>(&al[ks * 20 * 32]);
        #pragma unroll 2
        for (int jj = 0; jj < 20; ++jj) {
            float w = Wp[(size_t)jj * 1000];
            const float4* a4 = abase + jj * 8;
            #pragma unroll
            for (int q = 0; q < 8; ++q) {
                float4 av = a4[q];
                acc[q * 4 + 0] = fmaf(av.x, w, acc[q * 4 + 0]);
                acc[q * 4 + 1] = fmaf(av.y, w, acc[q * 4 + 1]);
                acc[q * 4 + 2] = fmaf(av.z, w, acc[q * 4 + 2]);
                acc[q * 4 + 3] = fmaf(av.w, w, acc[q * 4 + 3]);
            }
        }
    }
    if (ks == 1 && hh < 125) {
        #pragma unroll
        for (int b = 0; b < 32; ++b) redg[b * 128 + hh] = acc[b];
    }
    __syncthreads();
    if (ks == 0 && hh < 125) {
        int h = hs * 125 + hh;
        float* pp = pout + (size_t)kc * 32000 + h;
        #pragma unroll
        for (int b = 0; b < 32; ++b) pp[(size_t)b * 1000] = acc[b] + redg[b * 128 + hh];
    }
}

// dual-weight variant: layer-3 reduce+leaky(+count) staged, then K and V partials
__global__ __launch_bounds__(256) void k_gspred_kv(
    const float* __restrict__ pin, const float* __restrict__ bias,
    const float* __restrict__ mem_old, float* __restrict__ mem_new,
    const float* __restrict__ Wk, const float* __restrict__ Wv,
    float* __restrict__ pk, float* __restrict__ pv, float* cnt)
{
    int hs = blockIdx.x, kc = blockIdx.y, tid = threadIdx.x;
    int j0 = kc * 40;
    __shared__ __align__(16) float al[1280];
    __shared__ float redk[32 * 128];
    __shared__ float redv[32 * 128];
    __shared__ float csum[4];
    float localc = 0.f;
    for (int e = tid; e < 1280; e += 256) {
        int jj = e % 40, b = e / 40;
        int idx = b * 1000 + j0 + jj;
        float a = bias[j0 + jj];
        #pragma unroll 5
        for (int c = 0; c < 25; ++c) a += pin[(size_t)c * 32000 + idx];
        float m = mem_old[idx];
        float r = (m - kTHR > 0.f) ? kTHR : 0.f;
        float mn = __fsub_rn(__fadd_rn(__fmul_rn(kBETA, m), a), r);
        float s = (mn - kTHR > 0.f) ? 1.f : 0.f;
        al[jj * 32 + b] = s;
        if (hs == 0) { mem_new[idx] = mn; localc += s; }
    }
    for (int off = 32; off; off >>= 1) localc += __shfl_down(localc, off, 64);
    if ((tid & 63) == 0) csum[tid >> 6] = localc;
    __syncthreads();
    if (tid == 0 && hs == 0) {
        float tot = csum[0] + csum[1] + csum[2] + csum[3];
        if (tot != 0.f) atomicAdd(cnt, tot);
    }
    int ks = tid >> 7, hh = tid & 127;
    float ak[32], av2[32];
    #pragma unroll
    for (int b = 0; b < 32; ++b) { ak[b] = 0.f; av2[b] = 0.f; }
    if (hh < 125) {
        int h = hs * 125 + hh;
        const float* wkp = Wk + (size_t)(j0 + ks * 20) * 1000 + h;
        const float* wvp = Wv + (size_t)(j0 + ks * 20) * 1000 + h;
        const float4* abase = reinterpret_cast<const float4*>(&al[ks * 20 * 32]);
        #pragma unroll 2
        for (int jj = 0; jj < 20; ++jj) {
            float wk = wkp[(size_t)jj * 1000];
            float wv = wvp[(size_t)jj * 1000];
            const float4* a4 = abase + jj * 8;
            #pragma unroll
            for (int q = 0; q < 8; ++q) {
                float4 av = a4[q];
                ak[q * 4 + 0] = fmaf(av.x, wk, ak[q * 4 + 0]);
                ak[q * 4 + 1] = fmaf(av.y, wk, ak[q * 4 + 1]);
                ak[q * 4 + 2] = fmaf(av.z, wk, ak[q * 4 + 2]);
                ak[q * 4 + 3] = fmaf(av.w, wk, ak[q * 4 + 3]);
                av2[q * 4 + 0] = fmaf(av.x, wv, av2[q * 4 + 0]);
                av2[q * 4 + 1] = fmaf(av.y, wv, av2[q * 4 + 1]);
                av2[q * 4 + 2] = fmaf(av.z, wv, av2[q * 4 + 2]);
                av2[q * 4 + 3] = fmaf(av.w, wv, av2[q * 4 + 3]);
            }
        }
    }
    if (ks == 1 && hh < 125) {
        #pragma unroll
        for (int b = 0; b < 32; ++b) { redk[b * 128 + hh] = ak[b]; redv[b * 128 + hh] = av2[b]; }
    }
    __syncthreads();
    if (ks == 0 && hh < 125) {
        int h = hs * 125 + hh;
        float* ppk = pk + (size_t)kc * 32000 + h;
        float* ppv = pv + (size_t)kc * 32000 + h;
        #pragma unroll
        for (int b = 0; b < 32; ++b) {
            ppk[(size_t)b * 1000] = ak[b] + redk[b * 128 + hh];
            ppv[(size_t)b * 1000] = av2[b] + redv[b * 128 + hh];
        }
    }
}

// ---------------- attention: staged K/V reduce + fused q-GEMM + 2-way softmax + final ----------------
__global__ __launch_bounds__(256) void k_attnred(
    const float* __restrict__ pkk, const float* __restrict__ pvv,
    const float* __restrict__ bk, const float* __restrict__ bv,
    const float* __restrict__ spkr, const float* __restrict__ Wq,
    const float* __restrict__ bq, const float* __restrict__ Wo,
    const float* __restrict__ bo,
    float* __restrict__ patt, float* __restrict__ memo,
    float* __restrict__ oacc, const float* __restrict__ cnt,
    float* __restrict__ sc, float* __restrict__ dout,
    unsigned int* __restrict__ tick, int t)
{
    int it = blockIdx.x, b = blockIdx.y;
    int tid = threadIdx.x;
    __shared__ float kk[1000], vv[1000];
    __shared__ float sr[100];
    __shared__ float red[256];
    __shared__ float pden[256], pnum[256];
    __shared__ int isLast;
    float pmax = -3.4e38f, pmin = 3.4e38f;
    if (tid < 100) sr[tid] = spkr[b * 100 + tid];
    for (int h = tid; h < 1000; h += 256) {
        int idx = b * 1000 + h;
        float ak = bk[h], av = bv[h];
        #pragma unroll 5
        for (int c = 0; c < 25; ++c) {
            ak += pkk[(size_t)c * 32000 + idx];
            av += pvv[(size_t)c * 32000 + idx];
        }
        kk[h] = ak; vv[h] = av;
        pmax = fmaxf(pmax, ak);
        pmin = fminf(pmin, ak);
    }
    red[tid] = pmax;
    __syncthreads();
    for (int s2 = 128; s2 > 0; s2 >>= 1) {
        if (tid < s2) red[tid] = fmaxf(red[tid], red[tid + s2]);
        __syncthreads();
    }
    float kmax = red[0];
    __syncthreads();
    red[tid] = pmin;
    __syncthreads();
    for (int s2 = 128; s2 > 0; s2 >>= 1) {
        if (tid < s2) red[tid] = fminf(red[tid], red[tid + s2]);
        __syncthreads();
    }
    float kmin = red[0];
    __syncthreads();

    // 2-way split softmax: lane half computes 500-j partial num/den
    int half = tid >> 7, lane = tid & 127;
    float den = 0.f, num = 0.f;
    if (lane < 125) {
        int i = it * 125 + lane;
        float qi = bq[i];
        for (int j = 0; j < 100; ++j) qi = fmaf(sr[j], Wq[j * 1000 + i], qi);
        float qs = qi / 31.62277660168379f;   // sqrt(1000)
        float m = (qs >= 0.f) ? qs * kmax : qs * kmin;
        int jb = half * 500;
        for (int j = 0; j < 500; ++j) {
            float e = __expf(fmaf(qs, kk[jb + j], -m));
            den += e;
            num = fmaf(e, vv[jb + j], num);
        }
    }
    pden[tid] = den; pnum[tid] = num;
    __syncthreads();
    float pw = 0.f;
    if (tid < 125) {
        float dsum = pden[tid] + pden[tid + 128];
        float nsum = pnum[tid] + pnum[tid + 128];
        pw = (nsum / dsum) * Wo[it * 125 + tid];
    }
    red[tid] = (tid < 125) ? pw : 0.f;
    __syncthreads();
    for (int s2 = 128; s2 > 0; s2 >>= 1) {
        if (tid < s2) red[tid] += red[tid + s2];
        __syncthreads();
    }
    if (tid == 0) patt[b * 8 + it] = red[0];
    __syncthreads();
    if (tid == 0) {
        __threadfence();
        unsigned r = atomicAdd(tick, 1u);
        isLast = (r == 255u) ? 1 : 0;
    }
    __syncthreads();
    if (isLast && tid < 64) {
        __threadfence();
        float s = 0.f;
        if (tid < 32) {
            float a = bo[0];
            for (int itx = 0; itx < 8; ++itx) a += patt[tid * 8 + itx];
            float m = memo[tid];
            float r = (m - kTHR > 0.f) ? kTHR : 0.f;
            float mn = __fsub_rn(__fadd_rn(__fmul_rn(kBETA, m), a), r);
            memo[tid] = mn;
            s = (mn - kTHR > 0.f) ? 1.f : 0.f;
            float oa = oacc[tid] + s;
            oacc[tid] = oa;
            if (t == 4) dout[tid] = oa / 5.0f;
        }
        unsigned long long msk = __ballot(s > 0.5f);
        float co = (float)__popcll(msk);
        if (tid == 0) {
            float total = sc[0];
            float prev = total;
            total = __fadd_rn(total, __fdiv_rn(cnt[0], 32000.f));
            total = __fadd_rn(total, __fdiv_rn(cnt[1], 32000.f));
            total = __fadd_rn(total, __fdiv_rn(cnt[2], 3200.f));
            total = __fadd_rn(total, __fdiv_rn(co, 32.f));
            float reg = sc[1];
            reg = __fadd_rn(reg, __fmul_rn(kLM, total));
            if (t > 0) reg = __fadd_rn(reg, __fmul_rn(kLM, fabsf(__fsub_rn(total, prev))));
            sc[0] = total; sc[1] = reg;
            if (t == 4) dout[32] = reg / 5.0f;
        }
    }
}

// ---------------- host ----------------
extern "C" void kernel_launch(void* const* d_in, const int* in_sizes, int n_in,
                              void* d_out, int out_size, void* d_ws, size_t ws_size,
                              hipStream_t stream)
{
    const float* data = (const float*)d_in[0];
    const float* Wpe  = (const float*)d_in[1];
    const float* bpe  = (const float*)d_in[2];
    const float* pos  = (const float*)d_in[3];
    const float* W1   = (const float*)d_in[4];
    const float* b1   = (const float*)d_in[5];
    const float* W2   = (const float*)d_in[6];
    const float* b2   = (const float*)d_in[7];
    const float* W3   = (const float*)d_in[8];
    const float* b3   = (const float*)d_in[9];
    const float* WR   = (const float*)d_in[10];
    const float* bR   = (const float*)d_in[11];
    const float* Vw   = (const float*)d_in[12];
    const float* Vb   = (const float*)d_in[13];
    const float* Wq   = (const float*)d_in[14];
    const float* bq   = (const float*)d_in[15];
    const float* Wk   = (const float*)d_in[16];
    const float* bk   = (const float*)d_in[17];
    const float* Wv   = (const float*)d_in[18];
    const float* bv   = (const float*)d_in[19];
    const float* Wo   = (const float*)d_in[20];
    const float* bo   = (const float*)d_in[21];

    float* ws = (float*)d_ws;
    float* dout = (float*)d_out;

    float* xf    = ws + OFF_X;
    float* cur1  = ws + OFF_CUR1;
    float* mem1  = ws + OFF_MEM1;
    float* mem2a = ws + OFF_MEM2;
    float* mem3a = ws + OFF_MEM3;
    float* spk1b = ws + OFF_SPK1B;
    float* memr  = ws + OFF_MEMR;
    float* spkr  = ws + OFF_SPKR;
    float* memo  = ws + OFF_MEMO;
    float* patt  = ws + OFF_PATT;
    float* cntb  = ws + OFF_CNT;
    float* oacc  = ws + OFF_OACC;
    float* sc    = ws + OFF_SC;
    unsigned int* tick = (unsigned int*)(ws + OFF_TICK);
    float* part  = ws + OFF_PART;
    float* pg2   = ws + OFF_PG2;
    float* pg3   = ws + OFF_PG3;
    float* pkk   = ws + OFF_PKK;
    float* pvv   = ws + OFF_PVV;
    float* mem2b = ws + OFF_M2B;
    float* mem3b = ws + OFF_M3B;

    // chunk count for the big GEMM: cap 122 (tpc=6) -> 15.6 MB partials (L2-friendly)
    size_t ws_f = ws_size / 4;
    size_t avail = (ws_f > OFF_PART) ? (ws_f - OFF_PART) : 0;
    long nchunk_l = (long)(avail / 32000);
    int nchunk = (nchunk_l > 122) ? 122 : (int)nchunk_l;
    if (nchunk < 1) nchunk = 1;
    int tpc = (729 + nchunk - 1) / nchunk;
    nchunk = (729 + tpc - 1) / tpc;

    k_init<<<402, 256, 0, stream>>>(ws);
    k_patch<<<23328, 64, 0, stream>>>(data, Wpe, bpe, pos, xf);
    k_gemm1_part<<<dim3(nchunk, 2), 256, 0, stream>>>(xf, W1, part, tpc);
    k_gemm1_reduce<<<250, 128, 0, stream>>>(part, b1, cur1, nchunk);

    for (int t = 0; t < 5; ++t) {
        float* cnt = cntb + t * 4;
        float* m2o = (t & 1) ? mem2b : mem2a;
        float* m2n = (t & 1) ? mem2a : mem2b;
        float* m3o = (t & 1) ? mem3b : mem3a;
        float* m3n = (t & 1) ? mem3a : mem3b;

        // 1. double-leaky + RLeaky
        k_stepR<<<32, 256, 0, stream>>>(cur1, mem1, spk1b, WR, bR, Vw, Vb,
                                        memr, spkr, cnt + 0, cnt + 2);
        // 2. layer-2 GEMM partials: spk1b @ W2 -> pg2
        k_gsp<<<dim3(8, 25), 256, 0, stream>>>(spk1b, W2, pg2);
        // 3. reduce pg2 + leaky(mem2) staged, GEMM @ W3 -> pg3
        k_gspred<false><<<dim3(8, 25), 256, 0, stream>>>(
            pg2, b2, m2o, m2n, W3, pg3, nullptr);
        // 4. reduce pg3 + leaky(mem3)(+count) staged, GEMM @ Wk/Wv -> pkk, pvv
        k_gspred_kv<<<dim3(8, 25), 256, 0, stream>>>(
            pg3, b3, m3o, m3n, Wk, Wv, pkk, pvv, cnt + 1);
        // 5. attention: reduce K/V + fused q + 2-way softmax + last-block final
        k_attnred<<<dim3(8, 32), 256, 0, stream>>>(
            pkk, pvv, bk, bv, spkr, Wq, bq, Wo, bo,
            patt, memo, oacc, cnt, sc, dout, tick + t, t);
    }
    (void)in_sizes; (void)n_in; (void)out_size;
}

// Round 7
// 716.409 us; speedup vs baseline: 5.5613x; 1.0979x over previous
//
#include <hip/hip_runtime.h>

// ---------------- workspace layout (float offsets) ----------------
#define OFF_X     0          // x_flat [32][46656]
#define OFF_CUR1  1492992    // [32][1000]
#define OFF_MEM1  1524992    // [32][1000]
#define OFF_MEM2  1556992    // [32][1000]  (slot A)
#define OFF_MEM3  1588992    // [32][1000]  (slot A)
#define OFF_SPK1B 1652992    // [32][1000]
#define OFF_MEMR  1844992    // [32][100]
#define OFF_SPKR  1848192    // [32][100]
#define OFF_MEMO  1851392    // [32]
#define OFF_PATT  1851424    // [32][8]
#define OFF_CNT   1851680    // [5][4] spike counters
#define OFF_OACC  1851700    // [32]
#define OFF_SC    1851732    // total, reg
#define OFF_TICK  1851736    // [5] uint ticket counters (one per step)
#define OFF_PART  1851744    // gemm1 partials [nchunk<=243][32][1000]
// step-loop buffers (overlay the gemm1 partial region after it's consumed)
#define OFF_PG2   OFF_PART               // [25][32][1000]
#define OFF_PG3   (OFF_PART + 800000)    // [25][32][1000]
#define OFF_PKK   (OFF_PART + 1600000)   // [25][32][1000]
#define OFF_PVV   (OFF_PART + 2400000)   // [25][32][1000]
#define OFF_M2B   (OFF_PART + 3200000)   // [32][1000] mem2 slot B
#define OFF_M3B   (OFF_PART + 3232000)   // [32][1000] mem3 slot B

static constexpr float kBETA  = 0.8f;
static constexpr float kTHR   = 0.5f;
static constexpr float kBETAR = 0.95f;
static constexpr float kTHRR  = 1.0f;
static constexpr float kLM    = 0.0058f;

// ---------------- init: zero all persistent state ----------------
__global__ void k_init(float* ws) {
    int idx = blockIdx.x * 256 + threadIdx.x;
    if (idx < 96000) {
        ws[OFF_MEM1 + idx] = 0.f;                 // mem1, mem2, mem3 (slot A)
    } else {
        int j = idx - 96000;
        if (j < 6752) ws[OFF_MEMR + j] = 0.f;     // mem_r..sc + tick counters
    }
}

// ---------------- patch embed ----------------
__global__ __launch_bounds__(64) void k_patch(
    const float* __restrict__ data, const float* __restrict__ Wpe,
    const float* __restrict__ bpe, const float* __restrict__ pos,
    float* __restrict__ xf)
{
    int bp = blockIdx.x;
    int b = bp / 729, p = bp % 729;
    int pr = p / 27, pc = p % 27;
    int tid = threadIdx.x;
    __shared__ float patch[256];
    const float* db = data + (size_t)b * 50176;
    for (int c = tid; c < 256; c += 64) {
        int ph = c >> 4, pw = c & 15;
        patch[c] = db[(pr * 8 + ph) * 224 + pc * 8 + pw];
    }
    __syncthreads();
    float acc = bpe[tid] + pos[p * 64 + tid];
    for (int c = 0; c < 256; ++c)
        acc = fmaf(patch[c], Wpe[c * 64 + tid], acc);
    xf[(size_t)b * 46656 + p * 64 + tid] = acc;
}

// ---------------- big GEMM partials: W1 read once AND high occupancy ----------------
// grid (243 kchunk, 4 hg), 256 thr, 1 h-col/thread, acc[32] (~50 VGPR).
// 972 blocks = 3.8 waves/SIMD (vs 244 = 0.95 in R6). K-chunks x h-groups are
// DISJOINT W1 partitions -> W1 still streamed exactly once (186 MB).
__global__ __launch_bounds__(256) void k_gemm1_part(
    const float* __restrict__ xf, const float* __restrict__ W1,
    float* __restrict__ part, int tpc)
{
    int chunk = blockIdx.x;
    int hg = blockIdx.y;
    int t0 = chunk * tpc;
    int t1 = t0 + tpc; if (t1 > 729) t1 = 729;
    int tid = threadIdx.x;
    __shared__ float xs[2048];           // [32 b][64 i]
    float acc[32];
    #pragma unroll
    for (int b = 0; b < 32; ++b) acc[b] = 0.f;

    const int hbase = hg * 250;
    const bool ok = tid < 250;
    const int h = hbase + (ok ? tid : 0);
    for (int tt = t0; tt < t1; ++tt) {
        int i0 = tt * 64;
        __syncthreads();
        for (int l = tid; l < 2048; l += 256)
            xs[l] = xf[(size_t)(l >> 6) * 46656 + i0 + (l & 63)];
        __syncthreads();
        for (int ii4 = 0; ii4 < 16; ++ii4) {
            int i = i0 + ii4 * 4;
            const float* col = W1 + (size_t)i * 1000 + h;
            float w0 = col[0], w1v = col[1000], w2 = col[2000], w3 = col[3000];
            #pragma unroll
            for (int b = 0; b < 32; ++b) {
                float4 xv = *reinterpret_cast<const float4*>(&xs[b * 64 + ii4 * 4]);
                float a = acc[b];
                a = fmaf(xv.x, w0, a);
                a = fmaf(xv.y, w1v, a);
                a = fmaf(xv.z, w2, a);
                a = fmaf(xv.w, w3, a);
                acc[b] = a;
            }
        }
    }
    if (ok) {
        float* pc = part + (size_t)chunk * 32000 + hbase + tid;
        #pragma unroll
        for (int b = 0; b < 32; ++b) pc[b * 1000] = acc[b];
    }
}

__global__ void k_gemm1_reduce(const float* __restrict__ part,
                               const float* __restrict__ b1,
                               float* __restrict__ cur1, int nchunk)
{
    int idx = blockIdx.x * 128 + threadIdx.x;   // 250 blocks x 128
    if (idx >= 32000) return;
    int h = idx % 1000;
    float a = b1[h];
    for (int c = 0; c < nchunk; ++c) a += part[(size_t)c * 32000 + idx];
    cur1[idx] = a;
}

// ---------------- fused stepA (double leaky) + RLeaky (proven) ----------------
__global__ __launch_bounds__(256) void k_stepR(
    const float* __restrict__ cur1, float* __restrict__ mem1,
    float* __restrict__ spk1b,
    const float* __restrict__ WR, const float* __restrict__ bR,
    const float* __restrict__ Vw, const float* __restrict__ Vb,
    float* __restrict__ mem_r, float* __restrict__ spk_r,
    float* cnt0, float* cnt2)
{
    int b = blockIdx.x;
    int tid = threadIdx.x;
    __shared__ float s1[1000];
    __shared__ float sr[100];
    __shared__ float red2[2][128];
    __shared__ float csum[4];

    float localc = 0.f;
    if (tid < 250) {
        int base = b * 1000 + tid * 4;
        float4 m4 = *reinterpret_cast<const float4*>(&mem1[base]);
        float4 c4 = *reinterpret_cast<const float4*>(&cur1[base]);
        float mm[4] = {m4.x, m4.y, m4.z, m4.w};
        float cc[4] = {c4.x, c4.y, c4.z, c4.w};
        float mb[4], sb[4];
        #pragma unroll
        for (int q = 0; q < 4; ++q) {
            float m = mm[q], c = cc[q];
            float r1 = (m - kTHR > 0.f) ? kTHR : 0.f;
            float ma = __fsub_rn(__fadd_rn(__fmul_rn(kBETA, m), c), r1);
            float s  = (ma - kTHR > 0.f) ? 1.f : 0.f;
            float r2 = __fmul_rn(s, kTHR);
            float mv = __fsub_rn(__fadd_rn(__fmul_rn(kBETA, ma), c), r2);
            sb[q] = (mv - kTHR > 0.f) ? 1.f : 0.f;
            mb[q] = mv;
            s1[tid * 4 + q] = s;
            localc += s;
        }
        *reinterpret_cast<float4*>(&mem1[base])  = make_float4(mb[0], mb[1], mb[2], mb[3]);
        *reinterpret_cast<float4*>(&spk1b[base]) = make_float4(sb[0], sb[1], sb[2], sb[3]);
    }
    if (tid < 100) sr[tid] = spk_r[b * 100 + tid];
    for (int off = 32; off; off >>= 1) localc += __shfl_down(localc, off, 64);
    if ((tid & 63) == 0) csum[tid >> 6] = localc;
    __syncthreads();
    if (tid == 0) atomicAdd(cnt0, csum[0] + csum[1] + csum[2] + csum[3]);

    int ks = tid >> 7, hh = tid & 127;
    float p = 0.f;
    if (hh < 100) {
        const float* wp = WR + (size_t)(ks * 500) * 100 + hh;
        int j0 = ks * 500;
        #pragma unroll 4
        for (int j = 0; j < 500; ++j) p = fmaf(s1[j0 + j], wp[(size_t)j * 100], p);
    }
    red2[ks][hh] = p;
    __syncthreads();
    float s = 0.f;
    if (tid < 100) {
        float acc = bR[tid] + red2[0][tid] + red2[1][tid];
        float rec = 0.f;
        for (int j = 0; j < 100; ++j) rec = fmaf(sr[j], Vw[j * 100 + tid], rec);
        float m = mem_r[b * 100 + tid];
        float r = (m - kTHRR > 0.f) ? kTHRR : 0.f;
        float mn = __fsub_rn(__fadd_rn(__fadd_rn(__fadd_rn(__fmul_rn(kBETAR, m), acc), rec), Vb[tid]), r);
        s = (mn - kTHRR > 0.f) ? 1.f : 0.f;
        mem_r[b * 100 + tid] = mn;
        spk_r[b * 100 + tid] = s;
    }
    unsigned long long msk = __ballot(s > 0.5f);
    if ((tid & 63) == 0) atomicAdd(cnt2, (float)__popcll(msk));
}

// ---------------- split-K spike-GEMM partial: 2-way K-split x 2-way batch split ----------------
// grid (8 hb, 25 kc, 2 bg). Weights L2-resident -> 2x W read is cheap; 400 blocks.
__global__ __launch_bounds__(256) void k_gsp(
    const float* __restrict__ A, const float* __restrict__ W,
    float* __restrict__ part)
{
    int hb = blockIdx.x, kc = blockIdx.y, bg = blockIdx.z;
    int tid = threadIdx.x;
    int j0 = kc * 40;
    __shared__ __align__(16) float al[640];      // [40 jj][16 b]
    __shared__ float redg[16 * 128];
    for (int l = tid; l < 640; l += 256)
        al[l] = A[(size_t)(bg * 16 + (l & 15)) * 1000 + j0 + (l >> 4)];
    __syncthreads();
    int ks = tid >> 7, hh = tid & 127;
    float acc[16];
    #pragma unroll
    for (int b = 0; b < 16; ++b) acc[b] = 0.f;
    if (hh < 125) {
        int h = hb * 125 + hh;
        const float* Wp = W + (size_t)(j0 + ks * 20) * 1000 + h;
        const float4* abase = reinterpret_cast<const float4*>(&al[ks * 20 * 16]);
        #pragma unroll 2
        for (int jj = 0; jj < 20; ++jj) {
            float w = Wp[(size_t)jj * 1000];
            const float4* a4 = abase + jj * 4;
            #pragma unroll
            for (int q = 0; q < 4; ++q) {
                float4 av = a4[q];
                acc[q * 4 + 0] = fmaf(av.x, w, acc[q * 4 + 0]);
                acc[q * 4 + 1] = fmaf(av.y, w, acc[q * 4 + 1]);
                acc[q * 4 + 2] = fmaf(av.z, w, acc[q * 4 + 2]);
                acc[q * 4 + 3] = fmaf(av.w, w, acc[q * 4 + 3]);
            }
        }
    }
    if (ks == 1 && hh < 125) {
        #pragma unroll
        for (int b = 0; b < 16; ++b) redg[b * 128 + hh] = acc[b];
    }
    __syncthreads();
    if (ks == 0 && hh < 125) {
        int h = hb * 125 + hh;
        float* pp = part + (size_t)kc * 32000 + (size_t)(bg * 16) * 1000 + h;
        #pragma unroll
        for (int b = 0; b < 16; ++b) pp[(size_t)b * 1000] = acc[b] + redg[b * 128 + hh];
    }
}

// ---------------- reduce(prev partials)+leaky staged in LDS, then split GEMM ----------------
// grid (8 hs, 25 kc, 2 bg). hs==0 blocks write mem_new / count for their bg half.
template <bool COUNT>
__global__ __launch_bounds__(256) void k_gspred(
    const float* __restrict__ pin, const float* __restrict__ bias,
    const float* __restrict__ mem_old, float* __restrict__ mem_new,
    const float* __restrict__ W, float* __restrict__ pout, float* cnt)
{
    int hs = blockIdx.x, kc = blockIdx.y, bg = blockIdx.z;
    int tid = threadIdx.x;
    int j0 = kc * 40;
    __shared__ __align__(16) float al[640];
    __shared__ float redg[16 * 128];
    __shared__ float csum[4];
    float localc = 0.f;
    for (int e = tid; e < 640; e += 256) {
        int jj = e % 40, bi = e / 40;
        int idx = (bg * 16 + bi) * 1000 + j0 + jj;
        float a = bias[j0 + jj];
        #pragma unroll 5
        for (int c = 0; c < 25; ++c) a += pin[(size_t)c * 32000 + idx];
        float m = mem_old[idx];
        float r = (m - kTHR > 0.f) ? kTHR : 0.f;
        float mn = __fsub_rn(__fadd_rn(__fmul_rn(kBETA, m), a), r);
        float s = (mn - kTHR > 0.f) ? 1.f : 0.f;
        al[jj * 16 + bi] = s;
        if (hs == 0) { mem_new[idx] = mn; localc += s; }
    }
    if (COUNT) {
        for (int off = 32; off; off >>= 1) localc += __shfl_down(localc, off, 64);
        if ((tid & 63) == 0) csum[tid >> 6] = localc;
    }
    __syncthreads();
    if (COUNT && tid == 0 && hs == 0) {
        float tot = csum[0] + csum[1] + csum[2] + csum[3];
        if (tot != 0.f) atomicAdd(cnt, tot);
    }
    int ks = tid >> 7, hh = tid & 127;
    float acc[16];
    #pragma unroll
    for (int b = 0; b < 16; ++b) acc[b] = 0.f;
    if (hh < 125) {
        int h = hs * 125 + hh;
        const float* Wp = W + (size_t)(j0 + ks * 20) * 1000 + h;
        const float4* abase = reinterpret_cast<const float4*>(&al[ks * 20 * 16]);
        #pragma unroll 2
        for (int jj = 0; jj < 20; ++jj) {
            float w = Wp[(size_t)jj * 1000];
            const float4* a4 = abase + jj * 4;
            #pragma unroll
            for (int q = 0; q < 4; ++q) {
                float4 av = a4[q];
                acc[q * 4 + 0] = fmaf(av.x, w, acc[q * 4 + 0]);
                acc[q * 4 + 1] = fmaf(av.y, w, acc[q * 4 + 1]);
                acc[q * 4 + 2] = fmaf(av.z, w, acc[q * 4 + 2]);
                acc[q * 4 + 3] = fmaf(av.w, w, acc[q * 4 + 3]);
            }
        }
    }
    if (ks == 1 && hh < 125) {
        #pragma unroll
        for (int b = 0; b < 16; ++b) redg[b * 128 + hh] = acc[b];
    }
    __syncthreads();
    if (ks == 0 && hh < 125) {
        int h = hs * 125 + hh;
        float* pp = pout + (size_t)kc * 32000 + (size_t)(bg * 16) * 1000 + h;
        #pragma unroll
        for (int b = 0; b < 16; ++b) pp[(size_t)b * 1000] = acc[b] + redg[b * 128 + hh];
    }
}

// dual-weight variant: layer-3 reduce+leaky(+count) staged, then K and V partials
__global__ __launch_bounds__(256) void k_gspred_kv(
    const float* __restrict__ pin, const float* __restrict__ bias,
    const float* __restrict__ mem_old, float* __restrict__ mem_new,
    const float* __restrict__ Wk, const float* __restrict__ Wv,
    float* __restrict__ pk, float* __restrict__ pv, float* cnt)
{
    int hs = blockIdx.x, kc = blockIdx.y, bg = blockIdx.z;
    int tid = threadIdx.x;
    int j0 = kc * 40;
    __shared__ __align__(16) float al[640];
    __shared__ float redk[16 * 128];
    __shared__ float redv[16 * 128];
    __shared__ float csum[4];
    float localc = 0.f;
    for (int e = tid; e < 640; e += 256) {
        int jj = e % 40, bi = e / 40;
        int idx = (bg * 16 + bi) * 1000 + j0 + jj;
        float a = bias[j0 + jj];
        #pragma unroll 5
        for (int c = 0; c < 25; ++c) a += pin[(size_t)c * 32000 + idx];
        float m = mem_old[idx];
        float r = (m - kTHR > 0.f) ? kTHR : 0.f;
        float mn = __fsub_rn(__fadd_rn(__fmul_rn(kBETA, m), a), r);
        float s = (mn - kTHR > 0.f) ? 1.f : 0.f;
        al[jj * 16 + bi] = s;
        if (hs == 0) { mem_new[idx] = mn; localc += s; }
    }
    for (int off = 32; off; off >>= 1) localc += __shfl_down(localc, off, 64);
    if ((tid & 63) == 0) csum[tid >> 6] = localc;
    __syncthreads();
    if (tid == 0 && hs == 0) {
        float tot = csum[0] + csum[1] + csum[2] + csum[3];
        if (tot != 0.f) atomicAdd(cnt, tot);
    }
    int ks = tid >> 7, hh = tid & 127;
    float ak[16], av2[16];
    #pragma unroll
    for (int b = 0; b < 16; ++b) { ak[b] = 0.f; av2[b] = 0.f; }
    if (hh < 125) {
        int h = hs * 125 + hh;
        const float* wkp = Wk + (size_t)(j0 + ks * 20) * 1000 + h;
        const float* wvp = Wv + (size_t)(j0 + ks * 20) * 1000 + h;
        const float4* abase = reinterpret_cast<const float4*>(&al[ks * 20 * 16]);
        #pragma unroll 2
        for (int jj = 0; jj < 20; ++jj) {
            float wk = wkp[(size_t)jj * 1000];
            float wv = wvp[(size_t)jj * 1000];
            const float4* a4 = abase + jj * 4;
            #pragma unroll
            for (int q = 0; q < 4; ++q) {
                float4 av = a4[q];
                ak[q * 4 + 0] = fmaf(av.x, wk, ak[q * 4 + 0]);
                ak[q * 4 + 1] = fmaf(av.y, wk, ak[q * 4 + 1]);
                ak[q * 4 + 2] = fmaf(av.z, wk, ak[q * 4 + 2]);
                ak[q * 4 + 3] = fmaf(av.w, wk, ak[q * 4 + 3]);
                av2[q * 4 + 0] = fmaf(av.x, wv, av2[q * 4 + 0]);
                av2[q * 4 + 1] = fmaf(av.y, wv, av2[q * 4 + 1]);
                av2[q * 4 + 2] = fmaf(av.z, wv, av2[q * 4 + 2]);
                av2[q * 4 + 3] = fmaf(av.w, wv, av2[q * 4 + 3]);
            }
        }
    }
    if (ks == 1 && hh < 125) {
        #pragma unroll
        for (int b = 0; b < 16; ++b) { redk[b * 128 + hh] = ak[b]; redv[b * 128 + hh] = av2[b]; }
    }
    __syncthreads();
    if (ks == 0 && hh < 125) {
        int h = hs * 125 + hh;
        float* ppk = pk + (size_t)kc * 32000 + (size_t)(bg * 16) * 1000 + h;
        float* ppv = pv + (size_t)kc * 32000 + (size_t)(bg * 16) * 1000 + h;
        #pragma unroll
        for (int b = 0; b < 16; ++b) {
            ppk[(size_t)b * 1000] = ak[b] + redk[b * 128 + hh];
            ppv[(size_t)b * 1000] = av2[b] + redv[b * 128 + hh];
        }
    }
}

// ---------------- attention: staged K/V reduce + fused q-GEMM + 2-way softmax + final ----------------
__global__ __launch_bounds__(256) void k_attnred(
    const float* __restrict__ pkk, const float* __restrict__ pvv,
    const float* __restrict__ bk, const float* __restrict__ bv,
    const float* __restrict__ spkr, const float* __restrict__ Wq,
    const float* __restrict__ bq, const float* __restrict__ Wo,
    const float* __restrict__ bo,
    float* __restrict__ patt, float* __restrict__ memo,
    float* __restrict__ oacc, const float* __restrict__ cnt,
    float* __restrict__ sc, float* __restrict__ dout,
    unsigned int* __restrict__ tick, int t)
{
    int it = blockIdx.x, b = blockIdx.y;
    int tid = threadIdx.x;
    __shared__ float kk[1000], vv[1000];
    __shared__ float sr[100];
    __shared__ float red[256];
    __shared__ float pden[256], pnum[256];
    __shared__ int isLast;
    float pmax = -3.4e38f, pmin = 3.4e38f;
    if (tid < 100) sr[tid] = spkr[b * 100 + tid];
    for (int h = tid; h < 1000; h += 256) {
        int idx = b * 1000 + h;
        float ak = bk[h], av = bv[h];
        #pragma unroll 5
        for (int c = 0; c < 25; ++c) {
            ak += pkk[(size_t)c * 32000 + idx];
            av += pvv[(size_t)c * 32000 + idx];
        }
        kk[h] = ak; vv[h] = av;
        pmax = fmaxf(pmax, ak);
        pmin = fminf(pmin, ak);
    }
    red[tid] = pmax;
    __syncthreads();
    for (int s2 = 128; s2 > 0; s2 >>= 1) {
        if (tid < s2) red[tid] = fmaxf(red[tid], red[tid + s2]);
        __syncthreads();
    }
    float kmax = red[0];
    __syncthreads();
    red[tid] = pmin;
    __syncthreads();
    for (int s2 = 128; s2 > 0; s2 >>= 1) {
        if (tid < s2) red[tid] = fminf(red[tid], red[tid + s2]);
        __syncthreads();
    }
    float kmin = red[0];
    __syncthreads();

    // 2-way split softmax: lane half computes 500-j partial num/den
    int half = tid >> 7, lane = tid & 127;
    float den = 0.f, num = 0.f;
    if (lane < 125) {
        int i = it * 125 + lane;
        float qi = bq[i];
        for (int j = 0; j < 100; ++j) qi = fmaf(sr[j], Wq[j * 1000 + i], qi);
        float qs = qi / 31.62277660168379f;   // sqrt(1000)
        float m = (qs >= 0.f) ? qs * kmax : qs * kmin;
        int jb = half * 500;
        for (int j = 0; j < 500; ++j) {
            float e = __expf(fmaf(qs, kk[jb + j], -m));
            den += e;
            num = fmaf(e, vv[jb + j], num);
        }
    }
    pden[tid] = den; pnum[tid] = num;
    __syncthreads();
    float pw = 0.f;
    if (tid < 125) {
        float dsum = pden[tid] + pden[tid + 128];
        float nsum = pnum[tid] + pnum[tid + 128];
        pw = (nsum / dsum) * Wo[it * 125 + tid];
    }
    red[tid] = (tid < 125) ? pw : 0.f;
    __syncthreads();
    for (int s2 = 128; s2 > 0; s2 >>= 1) {
        if (tid < s2) red[tid] += red[tid + s2];
        __syncthreads();
    }
    if (tid == 0) patt[b * 8 + it] = red[0];
    __syncthreads();
    if (tid == 0) {
        __threadfence();
        unsigned r = atomicAdd(tick, 1u);
        isLast = (r == 255u) ? 1 : 0;
    }
    __syncthreads();
    if (isLast && tid < 64) {
        __threadfence();
        float s = 0.f;
        if (tid < 32) {
            float a = bo[0];
            for (int itx = 0; itx < 8; ++itx) a += patt[tid * 8 + itx];
            float m = memo[tid];
            float r = (m - kTHR > 0.f) ? kTHR : 0.f;
            float mn = __fsub_rn(__fadd_rn(__fmul_rn(kBETA, m), a), r);
            memo[tid] = mn;
            s = (mn - kTHR > 0.f) ? 1.f : 0.f;
            float oa = oacc[tid] + s;
            oacc[tid] = oa;
            if (t == 4) dout[tid] = oa / 5.0f;
        }
        unsigned long long msk = __ballot(s > 0.5f);
        float co = (float)__popcll(msk);
        if (tid == 0) {
            float total = sc[0];
            float prev = total;
            total = __fadd_rn(total, __fdiv_rn(cnt[0], 32000.f));
            total = __fadd_rn(total, __fdiv_rn(cnt[1], 32000.f));
            total = __fadd_rn(total, __fdiv_rn(cnt[2], 3200.f));
            total = __fadd_rn(total, __fdiv_rn(co, 32.f));
            float reg = sc[1];
            reg = __fadd_rn(reg, __fmul_rn(kLM, total));
            if (t > 0) reg = __fadd_rn(reg, __fmul_rn(kLM, fabsf(__fsub_rn(total, prev))));
            sc[0] = total; sc[1] = reg;
            if (t == 4) dout[32] = reg / 5.0f;
        }
    }
}

// ---------------- host ----------------
extern "C" void kernel_launch(void* const* d_in, const int* in_sizes, int n_in,
                              void* d_out, int out_size, void* d_ws, size_t ws_size,
                              hipStream_t stream)
{
    const float* data = (const float*)d_in[0];
    const float* Wpe  = (const float*)d_in[1];
    const float* bpe  = (const float*)d_in[2];
    const float* pos  = (const float*)d_in[3];
    const float* W1   = (const float*)d_in[4];
    const float* b1   = (const float*)d_in[5];
    const float* W2   = (const float*)d_in[6];
    const float* b2   = (const float*)d_in[7];
    const float* W3   = (const float*)d_in[8];
    const float* b3   = (const float*)d_in[9];
    const float* WR   = (const float*)d_in[10];
    const float* bR   = (const float*)d_in[11];
    const float* Vw   = (const float*)d_in[12];
    const float* Vb   = (const float*)d_in[13];
    const float* Wq   = (const float*)d_in[14];
    const float* bq   = (const float*)d_in[15];
    const float* Wk   = (const float*)d_in[16];
    const float* bk   = (const float*)d_in[17];
    const float* Wv   = (const float*)d_in[18];
    const float* bv   = (const float*)d_in[19];
    const float* Wo   = (const float*)d_in[20];
    const float* bo   = (const float*)d_in[21];

    float* ws = (float*)d_ws;
    float* dout = (float*)d_out;

    float* xf    = ws + OFF_X;
    float* cur1  = ws + OFF_CUR1;
    float* mem1  = ws + OFF_MEM1;
    float* mem2a = ws + OFF_MEM2;
    float* mem3a = ws + OFF_MEM3;
    float* spk1b = ws + OFF_SPK1B;
    float* memr  = ws + OFF_MEMR;
    float* spkr  = ws + OFF_SPKR;
    float* memo  = ws + OFF_MEMO;
    float* patt  = ws + OFF_PATT;
    float* cntb  = ws + OFF_CNT;
    float* oacc  = ws + OFF_OACC;
    float* sc    = ws + OFF_SC;
    unsigned int* tick = (unsigned int*)(ws + OFF_TICK);
    float* part  = ws + OFF_PART;
    float* pg2   = ws + OFF_PG2;
    float* pg3   = ws + OFF_PG3;
    float* pkk   = ws + OFF_PKK;
    float* pvv   = ws + OFF_PVV;
    float* mem2b = ws + OFF_M2B;
    float* mem3b = ws + OFF_M3B;

    // chunk count for the big GEMM: cap 243 (tpc=3) -> 972 blocks, 31 MB partials
    size_t ws_f = ws_size / 4;
    size_t avail = (ws_f > OFF_PART) ? (ws_f - OFF_PART) : 0;
    long nchunk_l = (long)(avail / 32000);
    int nchunk = (nchunk_l > 243) ? 243 : (int)nchunk_l;
    if (nchunk < 1) nchunk = 1;
    int tpc = (729 + nchunk - 1) / nchunk;
    nchunk = (729 + tpc - 1) / tpc;

    k_init<<<402, 256, 0, stream>>>(ws);
    k_patch<<<23328, 64, 0, stream>>>(data, Wpe, bpe, pos, xf);
    k_gemm1_part<<<dim3(nchunk, 4), 256, 0, stream>>>(xf, W1, part, tpc);
    k_gemm1_reduce<<<250, 128, 0, stream>>>(part, b1, cur1, nchunk);

    for (int t = 0; t < 5; ++t) {
        float* cnt = cntb + t * 4;
        float* m2o = (t & 1) ? mem2b : mem2a;
        float* m2n = (t & 1) ? mem2a : mem2b;
        float* m3o = (t & 1) ? mem3b : mem3a;
        float* m3n = (t & 1) ? mem3a : mem3b;

        // 1. double-leaky + RLeaky
        k_stepR<<<32, 256, 0, stream>>>(cur1, mem1, spk1b, WR, bR, Vw, Vb,
                                        memr, spkr, cnt + 0, cnt + 2);
        // 2. layer-2 GEMM partials: spk1b @ W2 -> pg2
        k_gsp<<<dim3(8, 25, 2), 256, 0, stream>>>(spk1b, W2, pg2);
        // 3. reduce pg2 + leaky(mem2) staged, GEMM @ W3 -> pg3
        k_gspred<false><<<dim3(8, 25, 2), 256, 0, stream>>>(
            pg2, b2, m2o, m2n, W3, pg3, nullptr);
        // 4. reduce pg3 + leaky(mem3)(+count) staged, GEMM @ Wk/Wv -> pkk, pvv
        k_gspred_kv<<<dim3(8, 25, 2), 256, 0, stream>>>(
            pg3, b3, m3o, m3n, Wk, Wv, pkk, pvv, cnt + 1);
        // 5. attention: reduce K/V + fused q + 2-way softmax + last-block final
        k_attnred<<<dim3(8, 32), 256, 0, stream>>>(
            pkk, pvv, bk, bv, spkr, Wq, bq, Wo, bo,
            patt, memo, oacc, cnt, sc, dout, tick + t, t);
    }
    (void)in_sizes; (void)n_in; (void)out_size;
}

// Round 8
// 587.607 us; speedup vs baseline: 6.7803x; 1.2192x over previous
//
#include <hip/hip_runtime.h>

// ---------------- workspace layout (float offsets) ----------------
#define OFF_X     0          // x_flat [32][46656]
#define OFF_CUR1  1492992    // [32][1000]
#define OFF_MEM1  1524992    // [32][1000]
#define OFF_MEM2  1556992    // [32][1000]  (slot A)
#define OFF_MEM3  1588992    // [32][1000]  (slot A)
#define OFF_SPK1B 1652992    // [32][1000]
#define OFF_MEMR  1844992    // [32][100]
#define OFF_SPKR  1848192    // [32][100]
#define OFF_MEMO  1851392    // [32]
#define OFF_PATT  1851424    // [32][8]
#define OFF_CNT   1851680    // [5][4] spike counters
#define OFF_OACC  1851700    // [32]
#define OFF_SC    1851732    // total, reg
#define OFF_TICK  1851736    // [5] uint ticket counters (one per step)
#define OFF_PART  1851744    // gemm1 partials [nchunk<=365][32][1000]
// step-loop buffers (overlay the gemm1 partial region after it's consumed)
#define OFF_PG2   OFF_PART               // [25][32][1000]
#define OFF_PG3   (OFF_PART + 800000)    // [25][32][1000]
#define OFF_PKK   (OFF_PART + 1600000)   // [25][32][1000]
#define OFF_PVV   (OFF_PART + 2400000)   // [25][32][1000]
#define OFF_M2B   (OFF_PART + 3200000)   // [32][1000] mem2 slot B
#define OFF_M3B   (OFF_PART + 3232000)   // [32][1000] mem3 slot B

static constexpr float kBETA  = 0.8f;
static constexpr float kTHR   = 0.5f;
static constexpr float kBETAR = 0.95f;
static constexpr float kTHRR  = 1.0f;
static constexpr float kLM    = 0.0058f;

// ---------------- init: zero all persistent state ----------------
__global__ void k_init(float* ws) {
    int idx = blockIdx.x * 256 + threadIdx.x;
    if (idx < 96000) {
        ws[OFF_MEM1 + idx] = 0.f;                 // mem1, mem2, mem3 (slot A)
    } else {
        int j = idx - 96000;
        if (j < 6752) ws[OFF_MEMR + j] = 0.f;     // mem_r..sc + tick counters
    }
}

// ---------------- patch embed ----------------
__global__ __launch_bounds__(64) void k_patch(
    const float* __restrict__ data, const float* __restrict__ Wpe,
    const float* __restrict__ bpe, const float* __restrict__ pos,
    float* __restrict__ xf)
{
    int bp = blockIdx.x;
    int b = bp / 729, p = bp % 729;
    int pr = p / 27, pc = p % 27;
    int tid = threadIdx.x;
    __shared__ float patch[256];
    const float* db = data + (size_t)b * 50176;
    for (int c = tid; c < 256; c += 64) {
        int ph = c >> 4, pw = c & 15;
        patch[c] = db[(pr * 8 + ph) * 224 + pc * 8 + pw];
    }
    __syncthreads();
    float acc = bpe[tid] + pos[p * 64 + tid];
    for (int c = 0; c < 256; ++c)
        acc = fmaf(patch[c], Wpe[c * 64 + tid], acc);
    xf[(size_t)b * 46656 + p * 64 + tid] = acc;
}

// ---------------- big GEMM partials: W1 once, 2 cols/thread, 730 blocks ----------------
// grid (365 kchunk, 2 hg), 256 thr. 2 h-cols/thread -> 8 FMA per ds_read_b128
// (FMA-bound mix, R6) at 2.85 waves/SIMD (R7-level occupancy).
__global__ __launch_bounds__(256) void k_gemm1_part(
    const float* __restrict__ xf, const float* __restrict__ W1,
    float* __restrict__ part, int tpc)
{
    int chunk = blockIdx.x;
    int hg = blockIdx.y;
    int t0 = chunk * tpc;
    int t1 = t0 + tpc; if (t1 > 729) t1 = 729;
    int tid = threadIdx.x;
    __shared__ float xs[2048];           // [32 b][64 i]
    float acc[32][2];
    #pragma unroll
    for (int b = 0; b < 32; ++b) { acc[b][0] = 0.f; acc[b][1] = 0.f; }

    const int hbase = hg * 500;
    const bool ok1 = (tid + 256) < 500;  // second col valid
    const int h0 = hbase + tid;
    const int h1 = hbase + (ok1 ? tid + 256 : 0);
    for (int tt = t0; tt < t1; ++tt) {
        int i0 = tt * 64;
        __syncthreads();
        for (int l = tid; l < 2048; l += 256)
            xs[l] = xf[(size_t)(l >> 6) * 46656 + i0 + (l & 63)];
        __syncthreads();
        for (int ii4 = 0; ii4 < 16; ++ii4) {
            int i = i0 + ii4 * 4;
            const float* c0 = W1 + (size_t)i * 1000 + h0;
            const float* c1 = W1 + (size_t)i * 1000 + h1;
            float w0a = c0[0], w1a = c0[1000], w2a = c0[2000], w3a = c0[3000];
            float w0b = ok1 ? c1[0]    : 0.f;
            float w1b = ok1 ? c1[1000] : 0.f;
            float w2b = ok1 ? c1[2000] : 0.f;
            float w3b = ok1 ? c1[3000] : 0.f;
            #pragma unroll
            for (int b = 0; b < 32; ++b) {
                float4 xv = *reinterpret_cast<const float4*>(&xs[b * 64 + ii4 * 4]);
                float a0 = acc[b][0], a1 = acc[b][1];
                a0 = fmaf(xv.x, w0a, a0);  a1 = fmaf(xv.x, w0b, a1);
                a0 = fmaf(xv.y, w1a, a0);  a1 = fmaf(xv.y, w1b, a1);
                a0 = fmaf(xv.z, w2a, a0);  a1 = fmaf(xv.z, w2b, a1);
                a0 = fmaf(xv.w, w3a, a0);  a1 = fmaf(xv.w, w3b, a1);
                acc[b][0] = a0; acc[b][1] = a1;
            }
        }
    }
    float* pc = part + (size_t)chunk * 32000 + hbase;
    #pragma unroll
    for (int b = 0; b < 32; ++b) {
        pc[b * 1000 + tid] = acc[b][0];
        if (ok1) pc[b * 1000 + tid + 256] = acc[b][1];
    }
}

__global__ void k_gemm1_reduce(const float* __restrict__ part,
                               const float* __restrict__ b1,
                               float* __restrict__ cur1, int nchunk)
{
    int idx = blockIdx.x * 128 + threadIdx.x;   // 250 blocks x 128
    if (idx >= 32000) return;
    int h = idx % 1000;
    float a = b1[h];
    for (int c = 0; c < nchunk; ++c) a += part[(size_t)c * 32000 + idx];
    cur1[idx] = a;
}

// ---------------- fused stepA (double leaky) + RLeaky, 512 thr, WR 4-way K-split ----------------
__global__ __launch_bounds__(512) void k_stepR(
    const float* __restrict__ cur1, float* __restrict__ mem1,
    float* __restrict__ spk1b,
    const float* __restrict__ WR, const float* __restrict__ bR,
    const float* __restrict__ Vw, const float* __restrict__ Vb,
    float* __restrict__ mem_r, float* __restrict__ spk_r,
    float* cnt0, float* cnt2)
{
    int b = blockIdx.x;
    int tid = threadIdx.x;
    __shared__ float s1[1000];
    __shared__ float sr[100];
    __shared__ float red2[4][128];
    __shared__ float csum[8];

    float localc = 0.f;
    if (tid < 250) {
        int base = b * 1000 + tid * 4;
        float4 m4 = *reinterpret_cast<const float4*>(&mem1[base]);
        float4 c4 = *reinterpret_cast<const float4*>(&cur1[base]);
        float mm[4] = {m4.x, m4.y, m4.z, m4.w};
        float cc[4] = {c4.x, c4.y, c4.z, c4.w};
        float mb[4], sb[4];
        #pragma unroll
        for (int q = 0; q < 4; ++q) {
            float m = mm[q], c = cc[q];
            float r1 = (m - kTHR > 0.f) ? kTHR : 0.f;
            float ma = __fsub_rn(__fadd_rn(__fmul_rn(kBETA, m), c), r1);
            float s  = (ma - kTHR > 0.f) ? 1.f : 0.f;
            float r2 = __fmul_rn(s, kTHR);
            float mv = __fsub_rn(__fadd_rn(__fmul_rn(kBETA, ma), c), r2);
            sb[q] = (mv - kTHR > 0.f) ? 1.f : 0.f;
            mb[q] = mv;
            s1[tid * 4 + q] = s;
            localc += s;
        }
        *reinterpret_cast<float4*>(&mem1[base])  = make_float4(mb[0], mb[1], mb[2], mb[3]);
        *reinterpret_cast<float4*>(&spk1b[base]) = make_float4(sb[0], sb[1], sb[2], sb[3]);
    }
    if (tid < 100) sr[tid] = spk_r[b * 100 + tid];
    for (int off = 32; off; off >>= 1) localc += __shfl_down(localc, off, 64);
    if ((tid & 63) == 0) csum[tid >> 6] = localc;
    __syncthreads();
    if (tid == 0) {
        float cs = 0.f;
        #pragma unroll
        for (int w = 0; w < 8; ++w) cs += csum[w];
        atomicAdd(cnt0, cs);
    }

    // WR-GEMM: 4-way K-split (125-iter chains)
    int ks = tid >> 7, hh = tid & 127;
    float p = 0.f;
    if (hh < 100) {
        const float* wp = WR + (size_t)(ks * 250) * 100 + hh;
        int j0 = ks * 250;
        #pragma unroll 5
        for (int j = 0; j < 250; ++j) p = fmaf(s1[j0 + j], wp[(size_t)j * 100], p);
    }
    red2[ks][hh] = p;
    __syncthreads();
    float s = 0.f;
    if (tid < 100) {
        float acc = bR[tid] + ((red2[0][tid] + red2[1][tid]) + (red2[2][tid] + red2[3][tid]));
        float rec = 0.f;
        for (int j = 0; j < 100; ++j) rec = fmaf(sr[j], Vw[j * 100 + tid], rec);
        float m = mem_r[b * 100 + tid];
        float r = (m - kTHRR > 0.f) ? kTHRR : 0.f;
        float mn = __fsub_rn(__fadd_rn(__fadd_rn(__fadd_rn(__fmul_rn(kBETAR, m), acc), rec), Vb[tid]), r);
        s = (mn - kTHRR > 0.f) ? 1.f : 0.f;
        mem_r[b * 100 + tid] = mn;
        spk_r[b * 100 + tid] = s;
    }
    unsigned long long msk = __ballot(s > 0.5f);
    if ((tid & 63) == 0) {
        int pc2 = __popcll(msk);
        if (pc2) atomicAdd(cnt2, (float)pc2);
    }
}

// ---------------- split-K spike-GEMM partial: 2-way K x 4-way batch split ----------------
// grid (8 hb, 25 kc, 4 bg) = 800 blocks = 3.1 waves/SIMD. W L2-resident (4x read cheap).
__global__ __launch_bounds__(256) void k_gsp(
    const float* __restrict__ A, const float* __restrict__ W,
    float* __restrict__ part)
{
    int hb = blockIdx.x, kc = blockIdx.y, bg = blockIdx.z;
    int tid = threadIdx.x;
    int j0 = kc * 40;
    __shared__ __align__(16) float al[320];      // [40 jj][8 b]
    __shared__ float redg[8 * 128];
    for (int l = tid; l < 320; l += 256)
        al[l] = A[(size_t)(bg * 8 + (l & 7)) * 1000 + j0 + (l >> 3)];
    __syncthreads();
    int ks = tid >> 7, hh = tid & 127;
    float acc[8];
    #pragma unroll
    for (int b = 0; b < 8; ++b) acc[b] = 0.f;
    if (hh < 125) {
        int h = hb * 125 + hh;
        const float* Wp = W + (size_t)(j0 + ks * 20) * 1000 + h;
        const float4* abase = reinterpret_cast<const float4*>(&al[ks * 20 * 8]);
        #pragma unroll 4
        for (int jj = 0; jj < 20; ++jj) {
            float w = Wp[(size_t)jj * 1000];
            const float4* a4 = abase + jj * 2;
            #pragma unroll
            for (int q = 0; q < 2; ++q) {
                float4 av = a4[q];
                acc[q * 4 + 0] = fmaf(av.x, w, acc[q * 4 + 0]);
                acc[q * 4 + 1] = fmaf(av.y, w, acc[q * 4 + 1]);
                acc[q * 4 + 2] = fmaf(av.z, w, acc[q * 4 + 2]);
                acc[q * 4 + 3] = fmaf(av.w, w, acc[q * 4 + 3]);
            }
        }
    }
    if (ks == 1 && hh < 125) {
        #pragma unroll
        for (int b = 0; b < 8; ++b) redg[b * 128 + hh] = acc[b];
    }
    __syncthreads();
    if (ks == 0 && hh < 125) {
        int h = hb * 125 + hh;
        float* pp = part + (size_t)kc * 32000 + (size_t)(bg * 8) * 1000 + h;
        #pragma unroll
        for (int b = 0; b < 8; ++b) pp[(size_t)b * 1000] = acc[b] + redg[b * 128 + hh];
    }
}

// ---------------- reduce(prev partials)+leaky staged in LDS, then split GEMM ----------------
// grid (8 hs, 25 kc, 4 bg). hs==0 writes mem_new/count for its (kc,bg) slice.
template <bool COUNT>
__global__ __launch_bounds__(256) void k_gspred(
    const float* __restrict__ pin, const float* __restrict__ bias,
    const float* __restrict__ mem_old, float* __restrict__ mem_new,
    const float* __restrict__ W, float* __restrict__ pout, float* cnt)
{
    int hs = blockIdx.x, kc = blockIdx.y, bg = blockIdx.z;
    int tid = threadIdx.x;
    int j0 = kc * 40;
    __shared__ __align__(16) float al[320];
    __shared__ float redg[8 * 128];
    __shared__ float csum[4];
    float localc = 0.f;
    if (tid < 320) {
        int jj = tid % 40, bi = tid / 40;
        // tid 0..255 covers bi 0..6 fully + part of 7; handle with loop below
    }
    for (int e = tid; e < 320; e += 256) {
        int jj = e % 40, bi = e / 40;
        int idx = (bg * 8 + bi) * 1000 + j0 + jj;
        float a = bias[j0 + jj];
        #pragma unroll 5
        for (int c = 0; c < 25; ++c) a += pin[(size_t)c * 32000 + idx];
        float m = mem_old[idx];
        float r = (m - kTHR > 0.f) ? kTHR : 0.f;
        float mn = __fsub_rn(__fadd_rn(__fmul_rn(kBETA, m), a), r);
        float s = (mn - kTHR > 0.f) ? 1.f : 0.f;
        al[jj * 8 + bi] = s;
        if (hs == 0) { mem_new[idx] = mn; localc += s; }
    }
    if (COUNT) {
        for (int off = 32; off; off >>= 1) localc += __shfl_down(localc, off, 64);
        if ((tid & 63) == 0) csum[tid >> 6] = localc;
    }
    __syncthreads();
    if (COUNT && tid == 0 && hs == 0) {
        float tot = csum[0] + csum[1] + csum[2] + csum[3];
        if (tot != 0.f) atomicAdd(cnt, tot);
    }
    int ks = tid >> 7, hh = tid & 127;
    float acc[8];
    #pragma unroll
    for (int b = 0; b < 8; ++b) acc[b] = 0.f;
    if (hh < 125) {
        int h = hs * 125 + hh;
        const float* Wp = W + (size_t)(j0 + ks * 20) * 1000 + h;
        const float4* abase = reinterpret_cast<const float4*>(&al[ks * 20 * 8]);
        #pragma unroll 4
        for (int jj = 0; jj < 20; ++jj) {
            float w = Wp[(size_t)jj * 1000];
            const float4* a4 = abase + jj * 2;
            #pragma unroll
            for (int q = 0; q < 2; ++q) {
                float4 av = a4[q];
                acc[q * 4 + 0] = fmaf(av.x, w, acc[q * 4 + 0]);
                acc[q * 4 + 1] = fmaf(av.y, w, acc[q * 4 + 1]);
                acc[q * 4 + 2] = fmaf(av.z, w, acc[q * 4 + 2]);
                acc[q * 4 + 3] = fmaf(av.w, w, acc[q * 4 + 3]);
            }
        }
    }
    if (ks == 1 && hh < 125) {
        #pragma unroll
        for (int b = 0; b < 8; ++b) redg[b * 128 + hh] = acc[b];
    }
    __syncthreads();
    if (ks == 0 && hh < 125) {
        int h = hs * 125 + hh;
        float* pp = pout + (size_t)kc * 32000 + (size_t)(bg * 8) * 1000 + h;
        #pragma unroll
        for (int b = 0; b < 8; ++b) pp[(size_t)b * 1000] = acc[b] + redg[b * 128 + hh];
    }
}

// dual-weight variant: layer-3 reduce+leaky(+count) staged, then K and V partials
__global__ __launch_bounds__(256) void k_gspred_kv(
    const float* __restrict__ pin, const float* __restrict__ bias,
    const float* __restrict__ mem_old, float* __restrict__ mem_new,
    const float* __restrict__ Wk, const float* __restrict__ Wv,
    float* __restrict__ pk, float* __restrict__ pv, float* cnt)
{
    int hs = blockIdx.x, kc = blockIdx.y, bg = blockIdx.z;
    int tid = threadIdx.x;
    int j0 = kc * 40;
    __shared__ __align__(16) float al[320];
    __shared__ float redk[8 * 128];
    __shared__ float redv[8 * 128];
    __shared__ float csum[4];
    float localc = 0.f;
    for (int e = tid; e < 320; e += 256) {
        int jj = e % 40, bi = e / 40;
        int idx = (bg * 8 + bi) * 1000 + j0 + jj;
        float a = bias[j0 + jj];
        #pragma unroll 5
        for (int c = 0; c < 25; ++c) a += pin[(size_t)c * 32000 + idx];
        float m = mem_old[idx];
        float r = (m - kTHR > 0.f) ? kTHR : 0.f;
        float mn = __fsub_rn(__fadd_rn(__fmul_rn(kBETA, m), a), r);
        float s = (mn - kTHR > 0.f) ? 1.f : 0.f;
        al[jj * 8 + bi] = s;
        if (hs == 0) { mem_new[idx] = mn; localc += s; }
    }
    for (int off = 32; off; off >>= 1) localc += __shfl_down(localc, off, 64);
    if ((tid & 63) == 0) csum[tid >> 6] = localc;
    __syncthreads();
    if (tid == 0 && hs == 0) {
        float tot = csum[0] + csum[1] + csum[2] + csum[3];
        if (tot != 0.f) atomicAdd(cnt, tot);
    }
    int ks = tid >> 7, hh = tid & 127;
    float ak[8], av2[8];
    #pragma unroll
    for (int b = 0; b < 8; ++b) { ak[b] = 0.f; av2[b] = 0.f; }
    if (hh < 125) {
        int h = hs * 125 + hh;
        const float* wkp = Wk + (size_t)(j0 + ks * 20) * 1000 + h;
        const float* wvp = Wv + (size_t)(j0 + ks * 20) * 1000 + h;
        const float4* abase = reinterpret_cast<const float4*>(&al[ks * 20 * 8]);
        #pragma unroll 4
        for (int jj = 0; jj < 20; ++jj) {
            float wk = wkp[(size_t)jj * 1000];
            float wv = wvp[(size_t)jj * 1000];
            const float4* a4 = abase + jj * 2;
            #pragma unroll
            for (int q = 0; q < 2; ++q) {
                float4 av = a4[q];
                ak[q * 4 + 0] = fmaf(av.x, wk, ak[q * 4 + 0]);
                ak[q * 4 + 1] = fmaf(av.y, wk, ak[q * 4 + 1]);
                ak[q * 4 + 2] = fmaf(av.z, wk, ak[q * 4 + 2]);
                ak[q * 4 + 3] = fmaf(av.w, wk, ak[q * 4 + 3]);
                av2[q * 4 + 0] = fmaf(av.x, wv, av2[q * 4 + 0]);
                av2[q * 4 + 1] = fmaf(av.y, wv, av2[q * 4 + 1]);
                av2[q * 4 + 2] = fmaf(av.z, wv, av2[q * 4 + 2]);
                av2[q * 4 + 3] = fmaf(av.w, wv, av2[q * 4 + 3]);
            }
        }
    }
    if (ks == 1 && hh < 125) {
        #pragma unroll
        for (int b = 0; b < 8; ++b) { redk[b * 128 + hh] = ak[b]; redv[b * 128 + hh] = av2[b]; }
    }
    __syncthreads();
    if (ks == 0 && hh < 125) {
        int h = hs * 125 + hh;
        float* ppk = pk + (size_t)kc * 32000 + (size_t)(bg * 8) * 1000 + h;
        float* ppv = pv + (size_t)kc * 32000 + (size_t)(bg * 8) * 1000 + h;
        #pragma unroll
        for (int b = 0; b < 8; ++b) {
            ppk[(size_t)b * 1000] = ak[b] + redk[b * 128 + hh];
            ppv[(size_t)b * 1000] = av2[b] + redv[b * 128 + hh];
        }
    }
}

// ---------------- attention: staged K/V reduce + fused q-GEMM + 2-way softmax + final ----------------
__global__ __launch_bounds__(256) void k_attnred(
    const float* __restrict__ pkk, const float* __restrict__ pvv,
    const float* __restrict__ bk, const float* __restrict__ bv,
    const float* __restrict__ spkr, const float* __restrict__ Wq,
    const float* __restrict__ bq, const float* __restrict__ Wo,
    const float* __restrict__ bo,
    float* __restrict__ patt, float* __restrict__ memo,
    float* __restrict__ oacc, const float* __restrict__ cnt,
    float* __restrict__ sc, float* __restrict__ dout,
    unsigned int* __restrict__ tick, int t)
{
    int it = blockIdx.x, b = blockIdx.y;
    int tid = threadIdx.x;
    __shared__ float kk[1000], vv[1000];
    __shared__ float sr[100];
    __shared__ float red[256];
    __shared__ float pden[256], pnum[256];
    __shared__ int isLast;
    float pmax = -3.4e38f, pmin = 3.4e38f;
    if (tid < 100) sr[tid] = spkr[b * 100 + tid];
    for (int h = tid; h < 1000; h += 256) {
        int idx = b * 1000 + h;
        float ak = bk[h], av = bv[h];
        #pragma unroll 5
        for (int c = 0; c < 25; ++c) {
            ak += pkk[(size_t)c * 32000 + idx];
            av += pvv[(size_t)c * 32000 + idx];
        }
        kk[h] = ak; vv[h] = av;
        pmax = fmaxf(pmax, ak);
        pmin = fminf(pmin, ak);
    }
    red[tid] = pmax;
    __syncthreads();
    for (int s2 = 128; s2 > 0; s2 >>= 1) {
        if (tid < s2) red[tid] = fmaxf(red[tid], red[tid + s2]);
        __syncthreads();
    }
    float kmax = red[0];
    __syncthreads();
    red[tid] = pmin;
    __syncthreads();
    for (int s2 = 128; s2 > 0; s2 >>= 1) {
        if (tid < s2) red[tid] = fminf(red[tid], red[tid + s2]);
        __syncthreads();
    }
    float kmin = red[0];
    __syncthreads();

    // 2-way split softmax: lane half computes 500-j partial num/den
    int half = tid >> 7, lane = tid & 127;
    float den = 0.f, num = 0.f;
    if (lane < 125) {
        int i = it * 125 + lane;
        float qi = bq[i];
        for (int j = 0; j < 100; ++j) qi = fmaf(sr[j], Wq[j * 1000 + i], qi);
        float qs = qi / 31.62277660168379f;   // sqrt(1000)
        float m = (qs >= 0.f) ? qs * kmax : qs * kmin;
        int jb = half * 500;
        for (int j = 0; j < 500; ++j) {
            float e = __expf(fmaf(qs, kk[jb + j], -m));
            den += e;
            num = fmaf(e, vv[jb + j], num);
        }
    }
    pden[tid] = den; pnum[tid] = num;
    __syncthreads();
    float pw = 0.f;
    if (tid < 125) {
        float dsum = pden[tid] + pden[tid + 128];
        float nsum = pnum[tid] + pnum[tid + 128];
        pw = (nsum / dsum) * Wo[it * 125 + tid];
    }
    red[tid] = (tid < 125) ? pw : 0.f;
    __syncthreads();
    for (int s2 = 128; s2 > 0; s2 >>= 1) {
        if (tid < s2) red[tid] += red[tid + s2];
        __syncthreads();
    }
    if (tid == 0) patt[b * 8 + it] = red[0];
    __syncthreads();
    if (tid == 0) {
        __threadfence();
        unsigned r = atomicAdd(tick, 1u);
        isLast = (r == 255u) ? 1 : 0;
    }
    __syncthreads();
    if (isLast && tid < 64) {
        __threadfence();
        float s = 0.f;
        if (tid < 32) {
            float a = bo[0];
            for (int itx = 0; itx < 8; ++itx) a += patt[tid * 8 + itx];
            float m = memo[tid];
            float r = (m - kTHR > 0.f) ? kTHR : 0.f;
            float mn = __fsub_rn(__fadd_rn(__fmul_rn(kBETA, m), a), r);
            memo[tid] = mn;
            s = (mn - kTHR > 0.f) ? 1.f : 0.f;
            float oa = oacc[tid] + s;
            oacc[tid] = oa;
            if (t == 4) dout[tid] = oa / 5.0f;
        }
        unsigned long long msk = __ballot(s > 0.5f);
        float co = (float)__popcll(msk);
        if (tid == 0) {
            float total = sc[0];
            float prev = total;
            total = __fadd_rn(total, __fdiv_rn(cnt[0], 32000.f));
            total = __fadd_rn(total, __fdiv_rn(cnt[1], 32000.f));
            total = __fadd_rn(total, __fdiv_rn(cnt[2], 3200.f));
            total = __fadd_rn(total, __fdiv_rn(co, 32.f));
            float reg = sc[1];
            reg = __fadd_rn(reg, __fmul_rn(kLM, total));
            if (t > 0) reg = __fadd_rn(reg, __fmul_rn(kLM, fabsf(__fsub_rn(total, prev))));
            sc[0] = total; sc[1] = reg;
            if (t == 4) dout[32] = reg / 5.0f;
        }
    }
}

// ---------------- host ----------------
extern "C" void kernel_launch(void* const* d_in, const int* in_sizes, int n_in,
                              void* d_out, int out_size, void* d_ws, size_t ws_size,
                              hipStream_t stream)
{
    const float* data = (const float*)d_in[0];
    const float* Wpe  = (const float*)d_in[1];
    const float* bpe  = (const float*)d_in[2];
    const float* pos  = (const float*)d_in[3];
    const float* W1   = (const float*)d_in[4];
    const float* b1   = (const float*)d_in[5];
    const float* W2   = (const float*)d_in[6];
    const float* b2   = (const float*)d_in[7];
    const float* W3   = (const float*)d_in[8];
    const float* b3   = (const float*)d_in[9];
    const float* WR   = (const float*)d_in[10];
    const float* bR   = (const float*)d_in[11];
    const float* Vw   = (const float*)d_in[12];
    const float* Vb   = (const float*)d_in[13];
    const float* Wq   = (const float*)d_in[14];
    const float* bq   = (const float*)d_in[15];
    const float* Wk   = (const float*)d_in[16];
    const float* bk   = (const float*)d_in[17];
    const float* Wv   = (const float*)d_in[18];
    const float* bv   = (const float*)d_in[19];
    const float* Wo   = (const float*)d_in[20];
    const float* bo   = (const float*)d_in[21];

    float* ws = (float*)d_ws;
    float* dout = (float*)d_out;

    float* xf    = ws + OFF_X;
    float* cur1  = ws + OFF_CUR1;
    float* mem1  = ws + OFF_MEM1;
    float* mem2a = ws + OFF_MEM2;
    float* mem3a = ws + OFF_MEM3;
    float* spk1b = ws + OFF_SPK1B;
    float* memr  = ws + OFF_MEMR;
    float* spkr  = ws + OFF_SPKR;
    float* memo  = ws + OFF_MEMO;
    float* patt  = ws + OFF_PATT;
    float* cntb  = ws + OFF_CNT;
    float* oacc  = ws + OFF_OACC;
    float* sc    = ws + OFF_SC;
    unsigned int* tick = (unsigned int*)(ws + OFF_TICK);
    float* part  = ws + OFF_PART;
    float* pg2   = ws + OFF_PG2;
    float* pg3   = ws + OFF_PG3;
    float* pkk   = ws + OFF_PKK;
    float* pvv   = ws + OFF_PVV;
    float* mem2b = ws + OFF_M2B;
    float* mem3b = ws + OFF_M3B;

    // chunk count for the big GEMM: cap 365 (tpc=2) -> 730 blocks, 46.7 MB partials
    size_t ws_f = ws_size / 4;
    size_t avail = (ws_f > OFF_PART) ? (ws_f - OFF_PART) : 0;
    long nchunk_l = (long)(avail / 32000);
    int nchunk = (nchunk_l > 365) ? 365 : (int)nchunk_l;
    if (nchunk < 1) nchunk = 1;
    int tpc = (729 + nchunk - 1) / nchunk;
    nchunk = (729 + tpc - 1) / tpc;

    k_init<<<402, 256, 0, stream>>>(ws);
    k_patch<<<23328, 64, 0, stream>>>(data, Wpe, bpe, pos, xf);
    k_gemm1_part<<<dim3(nchunk, 2), 256, 0, stream>>>(xf, W1, part, tpc);
    k_gemm1_reduce<<<250, 128, 0, stream>>>(part, b1, cur1, nchunk);

    for (int t = 0; t < 5; ++t) {
        float* cnt = cntb + t * 4;
        float* m2o = (t & 1) ? mem2b : mem2a;
        float* m2n = (t & 1) ? mem2a : mem2b;
        float* m3o = (t & 1) ? mem3b : mem3a;
        float* m3n = (t & 1) ? mem3a : mem3b;

        // 1. double-leaky + RLeaky (512 thr, 4-way WR split)
        k_stepR<<<32, 512, 0, stream>>>(cur1, mem1, spk1b, WR, bR, Vw, Vb,
                                        memr, spkr, cnt + 0, cnt + 2);
        // 2. layer-2 GEMM partials: spk1b @ W2 -> pg2
        k_gsp<<<dim3(8, 25, 4), 256, 0, stream>>>(spk1b, W2, pg2);
        // 3. reduce pg2 + leaky(mem2) staged, GEMM @ W3 -> pg3
        k_gspred<false><<<dim3(8, 25, 4), 256, 0, stream>>>(
            pg2, b2, m2o, m2n, W3, pg3, nullptr);
        // 4. reduce pg3 + leaky(mem3)(+count) staged, GEMM @ Wk/Wv -> pkk, pvv
        k_gspred_kv<<<dim3(8, 25, 4), 256, 0, stream>>>(
            pg3, b3, m3o, m3n, Wk, Wv, pkk, pvv, cnt + 1);
        // 5. attention: reduce K/V + fused q + 2-way softmax + last-block final
        k_attnred<<<dim3(8, 32), 256, 0, stream>>>(
            pkk, pvv, bk, bv, spkr, Wq, bq, Wo, bo,
            patt, memo, oacc, cnt, sc, dout, tick + t, t);
    }
    (void)in_sizes; (void)n_in; (void)out_size;
}

// Round 9
// 545.054 us; speedup vs baseline: 7.3096x; 1.0781x over previous
//
#include <hip/hip_runtime.h>

// ---------------- workspace layout (float offsets) ----------------
#define OFF_X     0          // x_flat [32][46656]
#define OFF_CUR1  1492992    // [32][1000]
#define OFF_MEM1  1524992    // [32][1000]
#define OFF_MEM2  1556992    // [32][1000]  (slot A)
#define OFF_MEM3  1588992    // [32][1000]  (slot A)
#define OFF_SPK1B 1652992    // [32][1000]
#define OFF_MEMR  1844992    // [32][100]
#define OFF_SPKR  1848192    // [32][100]
#define OFF_MEMO  1851392    // [32]
#define OFF_PATT  1851424    // [32][8]
#define OFF_CNT   1851680    // [5][4] spike counters
#define OFF_OACC  1851700    // [32]
#define OFF_SC    1851732    // total, reg
#define OFF_TICK  1851736    // [5] uint ticket counters (one per step)
#define OFF_PART  1851744    // gemm1 partials [nchunk<=365][32][1000]
// step-loop buffers (overlay the gemm1 partial region after it's consumed)
#define OFF_PG2   OFF_PART               // [25][32][1000]
#define OFF_PG3   (OFF_PART + 800000)    // [25][32][1000]
#define OFF_PKK   (OFF_PART + 1600000)   // [25][32][1000]
#define OFF_PVV   (OFF_PART + 2400000)   // [25][32][1000]
#define OFF_M2B   (OFF_PART + 3200000)   // [32][1000] mem2 slot B
#define OFF_M3B   (OFF_PART + 3232000)   // [32][1000] mem3 slot B

static constexpr float kBETA  = 0.8f;
static constexpr float kTHR   = 0.5f;
static constexpr float kBETAR = 0.95f;
static constexpr float kTHRR  = 1.0f;
static constexpr float kLM    = 0.0058f;

// ---------------- init: zero all persistent state ----------------
__global__ void k_init(float* ws) {
    int idx = blockIdx.x * 256 + threadIdx.x;
    if (idx < 96000) {
        ws[OFF_MEM1 + idx] = 0.f;                 // mem1, mem2, mem3 (slot A)
    } else {
        int j = idx - 96000;
        if (j < 6752) ws[OFF_MEMR + j] = 0.f;     // mem_r..sc + tick counters
    }
}

// ---------------- patch embed: one block per (batch, patch-row) ----------------
// 27 overlapping patches of a row share a 16x224 input slice. Lane = embed dim,
// so the input operand row[pc*8] is WAVE-UNIFORM (scalar load path); Wpe is read
// once per block -> Wpe L2 traffic 1.5 GB -> 55 MB vs the old per-patch blocks.
// FP order per output (c = 0..255 sequential) identical to previous kernel.
__global__ __launch_bounds__(64) void k_patch(
    const float* __restrict__ data, const float* __restrict__ Wpe,
    const float* __restrict__ bpe, const float* __restrict__ pos,
    float* __restrict__ xf)
{
    int b = blockIdx.x, pr = blockIdx.y;
    int tid = threadIdx.x;
    const float* db = data + (size_t)b * 50176 + pr * 1792;  // input row pr*8
    float bb = bpe[tid];
    float acc[27];
    #pragma unroll
    for (int pc = 0; pc < 27; ++pc)
        acc[pc] = bb + pos[(pr * 27 + pc) * 64 + tid];
    #pragma unroll 2
    for (int c = 0; c < 256; ++c) {
        float w = Wpe[c * 64 + tid];
        const float* row = db + (c >> 4) * 224 + (c & 15);
        #pragma unroll
        for (int pc = 0; pc < 27; ++pc)
            acc[pc] = fmaf(row[pc * 8], w, acc[pc]);
    }
    size_t obase = (size_t)b * 46656 + (size_t)pr * 27 * 64 + tid;
    #pragma unroll
    for (int pc = 0; pc < 27; ++pc)
        xf[obase + (size_t)pc * 64] = acc[pc];
}

// ---------------- big GEMM partials: W1 once, 2 cols/thread, 730 blocks ----------------
__global__ __launch_bounds__(256) void k_gemm1_part(
    const float* __restrict__ xf, const float* __restrict__ W1,
    float* __restrict__ part, int tpc)
{
    int chunk = blockIdx.x;
    int hg = blockIdx.y;
    int t0 = chunk * tpc;
    int t1 = t0 + tpc; if (t1 > 729) t1 = 729;
    int tid = threadIdx.x;
    __shared__ float xs[2048];           // [32 b][64 i]
    float acc[32][2];
    #pragma unroll
    for (int b = 0; b < 32; ++b) { acc[b][0] = 0.f; acc[b][1] = 0.f; }

    const int hbase = hg * 500;
    const bool ok1 = (tid + 256) < 500;  // second col valid
    const int h0 = hbase + tid;
    const int h1 = hbase + (ok1 ? tid + 256 : 0);
    for (int tt = t0; tt < t1; ++tt) {
        int i0 = tt * 64;
        __syncthreads();
        for (int l = tid; l < 2048; l += 256)
            xs[l] = xf[(size_t)(l >> 6) * 46656 + i0 + (l & 63)];
        __syncthreads();
        for (int ii4 = 0; ii4 < 16; ++ii4) {
            int i = i0 + ii4 * 4;
            const float* c0 = W1 + (size_t)i * 1000 + h0;
            const float* c1 = W1 + (size_t)i * 1000 + h1;
            float w0a = c0[0], w1a = c0[1000], w2a = c0[2000], w3a = c0[3000];
            float w0b = ok1 ? c1[0]    : 0.f;
            float w1b = ok1 ? c1[1000] : 0.f;
            float w2b = ok1 ? c1[2000] : 0.f;
            float w3b = ok1 ? c1[3000] : 0.f;
            #pragma unroll
            for (int b = 0; b < 32; ++b) {
                float4 xv = *reinterpret_cast<const float4*>(&xs[b * 64 + ii4 * 4]);
                float a0 = acc[b][0], a1 = acc[b][1];
                a0 = fmaf(xv.x, w0a, a0);  a1 = fmaf(xv.x, w0b, a1);
                a0 = fmaf(xv.y, w1a, a0);  a1 = fmaf(xv.y, w1b, a1);
                a0 = fmaf(xv.z, w2a, a0);  a1 = fmaf(xv.z, w2b, a1);
                a0 = fmaf(xv.w, w3a, a0);  a1 = fmaf(xv.w, w3b, a1);
                acc[b][0] = a0; acc[b][1] = a1;
            }
        }
    }
    float* pc = part + (size_t)chunk * 32000 + hbase;
    #pragma unroll
    for (int b = 0; b < 32; ++b) {
        pc[b * 1000 + tid] = acc[b][0];
        if (ok1) pc[b * 1000 + tid + 256] = acc[b][1];
    }
}

// ---------------- reduce with 4-way ILP on the chunk chain ----------------
__global__ void k_gemm1_reduce(const float* __restrict__ part,
                               const float* __restrict__ b1,
                               float* __restrict__ cur1, int nchunk)
{
    int idx = blockIdx.x * 128 + threadIdx.x;   // 250 blocks x 128
    if (idx >= 32000) return;
    int h = idx % 1000;
    float a0 = b1[h], a1 = 0.f, a2 = 0.f, a3 = 0.f;
    int c = 0;
    for (; c + 4 <= nchunk; c += 4) {
        a0 += part[(size_t)c * 32000 + idx];
        a1 += part[(size_t)(c + 1) * 32000 + idx];
        a2 += part[(size_t)(c + 2) * 32000 + idx];
        a3 += part[(size_t)(c + 3) * 32000 + idx];
    }
    for (; c < nchunk; ++c) a0 += part[(size_t)c * 32000 + idx];
    cur1[idx] = (a0 + a1) + (a2 + a3);
}

// ---------------- fused stepA (double leaky) + RLeaky, 512 thr, WR 4-way K-split ----------------
__global__ __launch_bounds__(512) void k_stepR(
    const float* __restrict__ cur1, float* __restrict__ mem1,
    float* __restrict__ spk1b,
    const float* __restrict__ WR, const float* __restrict__ bR,
    const float* __restrict__ Vw, const float* __restrict__ Vb,
    float* __restrict__ mem_r, float* __restrict__ spk_r,
    float* cnt0, float* cnt2)
{
    int b = blockIdx.x;
    int tid = threadIdx.x;
    __shared__ float s1[1000];
    __shared__ float sr[100];
    __shared__ float red2[4][128];
    __shared__ float csum[8];

    float localc = 0.f;
    if (tid < 250) {
        int base = b * 1000 + tid * 4;
        float4 m4 = *reinterpret_cast<const float4*>(&mem1[base]);
        float4 c4 = *reinterpret_cast<const float4*>(&cur1[base]);
        float mm[4] = {m4.x, m4.y, m4.z, m4.w};
        float cc[4] = {c4.x, c4.y, c4.z, c4.w};
        float mb[4], sb[4];
        #pragma unroll
        for (int q = 0; q < 4; ++q) {
            float m = mm[q], c = cc[q];
            float r1 = (m - kTHR > 0.f) ? kTHR : 0.f;
            float ma = __fsub_rn(__fadd_rn(__fmul_rn(kBETA, m), c), r1);
            float s  = (ma - kTHR > 0.f) ? 1.f : 0.f;
            float r2 = __fmul_rn(s, kTHR);
            float mv = __fsub_rn(__fadd_rn(__fmul_rn(kBETA, ma), c), r2);
            sb[q] = (mv - kTHR > 0.f) ? 1.f : 0.f;
            mb[q] = mv;
            s1[tid * 4 + q] = s;
            localc += s;
        }
        *reinterpret_cast<float4*>(&mem1[base])  = make_float4(mb[0], mb[1], mb[2], mb[3]);
        *reinterpret_cast<float4*>(&spk1b[base]) = make_float4(sb[0], sb[1], sb[2], sb[3]);
    }
    if (tid < 100) sr[tid] = spk_r[b * 100 + tid];
    for (int off = 32; off; off >>= 1) localc += __shfl_down(localc, off, 64);
    if ((tid & 63) == 0) csum[tid >> 6] = localc;
    __syncthreads();
    if (tid == 0) {
        float cs = 0.f;
        #pragma unroll
        for (int w = 0; w < 8; ++w) cs += csum[w];
        atomicAdd(cnt0, cs);
    }

    // WR-GEMM: 4-way K-split (125-iter chains)
    int ks = tid >> 7, hh = tid & 127;
    float p = 0.f;
    if (hh < 100) {
        const float* wp = WR + (size_t)(ks * 250) * 100 + hh;
        int j0 = ks * 250;
        #pragma unroll 5
        for (int j = 0; j < 250; ++j) p = fmaf(s1[j0 + j], wp[(size_t)j * 100], p);
    }
    red2[ks][hh] = p;
    __syncthreads();
    float s = 0.f;
    if (tid < 100) {
        float acc = bR[tid] + ((red2[0][tid] + red2[1][tid]) + (red2[2][tid] + red2[3][tid]));
        float rec = 0.f;
        for (int j = 0; j < 100; ++j) rec = fmaf(sr[j], Vw[j * 100 + tid], rec);
        float m = mem_r[b * 100 + tid];
        float r = (m - kTHRR > 0.f) ? kTHRR : 0.f;
        float mn = __fsub_rn(__fadd_rn(__fadd_rn(__fadd_rn(__fmul_rn(kBETAR, m), acc), rec), Vb[tid]), r);
        s = (mn - kTHRR > 0.f) ? 1.f : 0.f;
        mem_r[b * 100 + tid] = mn;
        spk_r[b * 100 + tid] = s;
    }
    unsigned long long msk = __ballot(s > 0.5f);
    if ((tid & 63) == 0) {
        int pc2 = __popcll(msk);
        if (pc2) atomicAdd(cnt2, (float)pc2);
    }
}

// ---------------- split-K spike-GEMM partial: 2-way K x 4-way batch split ----------------
__global__ __launch_bounds__(256) void k_gsp(
    const float* __restrict__ A, const float* __restrict__ W,
    float* __restrict__ part)
{
    int hb = blockIdx.x, kc = blockIdx.y, bg = blockIdx.z;
    int tid = threadIdx.x;
    int j0 = kc * 40;
    __shared__ __align__(16) float al[320];      // [40 jj][8 b]
    __shared__ float redg[8 * 128];
    for (int l = tid; l < 320; l += 256)
        al[l] = A[(size_t)(bg * 8 + (l & 7)) * 1000 + j0 + (l >> 3)];
    __syncthreads();
    int ks = tid >> 7, hh = tid & 127;
    float acc[8];
    #pragma unroll
    for (int b = 0; b < 8; ++b) acc[b] = 0.f;
    if (hh < 125) {
        int h = hb * 125 + hh;
        const float* Wp = W + (size_t)(j0 + ks * 20) * 1000 + h;
        const float4* abase = reinterpret_cast<const float4*>(&al[ks * 20 * 8]);
        #pragma unroll 4
        for (int jj = 0; jj < 20; ++jj) {
            float w = Wp[(size_t)jj * 1000];
            const float4* a4 = abase + jj * 2;
            #pragma unroll
            for (int q = 0; q < 2; ++q) {
                float4 av = a4[q];
                acc[q * 4 + 0] = fmaf(av.x, w, acc[q * 4 + 0]);
                acc[q * 4 + 1] = fmaf(av.y, w, acc[q * 4 + 1]);
                acc[q * 4 + 2] = fmaf(av.z, w, acc[q * 4 + 2]);
                acc[q * 4 + 3] = fmaf(av.w, w, acc[q * 4 + 3]);
            }
        }
    }
    if (ks == 1 && hh < 125) {
        #pragma unroll
        for (int b = 0; b < 8; ++b) redg[b * 128 + hh] = acc[b];
    }
    __syncthreads();
    if (ks == 0 && hh < 125) {
        int h = hb * 125 + hh;
        float* pp = part + (size_t)kc * 32000 + (size_t)(bg * 8) * 1000 + h;
        #pragma unroll
        for (int b = 0; b < 8; ++b) pp[(size_t)b * 1000] = acc[b] + redg[b * 128 + hh];
    }
}

// ---------------- reduce(prev partials)+leaky staged in LDS, then split GEMM ----------------
template <bool COUNT>
__global__ __launch_bounds__(256) void k_gspred(
    const float* __restrict__ pin, const float* __restrict__ bias,
    const float* __restrict__ mem_old, float* __restrict__ mem_new,
    const float* __restrict__ W, float* __restrict__ pout, float* cnt)
{
    int hs = blockIdx.x, kc = blockIdx.y, bg = blockIdx.z;
    int tid = threadIdx.x;
    int j0 = kc * 40;
    __shared__ __align__(16) float al[320];
    __shared__ float redg[8 * 128];
    __shared__ float csum[4];
    float localc = 0.f;
    for (int e = tid; e < 320; e += 256) {
        int jj = e % 40, bi = e / 40;
        int idx = (bg * 8 + bi) * 1000 + j0 + jj;
        float a = bias[j0 + jj];
        #pragma unroll 5
        for (int c = 0; c < 25; ++c) a += pin[(size_t)c * 32000 + idx];
        float m = mem_old[idx];
        float r = (m - kTHR > 0.f) ? kTHR : 0.f;
        float mn = __fsub_rn(__fadd_rn(__fmul_rn(kBETA, m), a), r);
        float s = (mn - kTHR > 0.f) ? 1.f : 0.f;
        al[jj * 8 + bi] = s;
        if (hs == 0) { mem_new[idx] = mn; localc += s; }
    }
    if (COUNT) {
        for (int off = 32; off; off >>= 1) localc += __shfl_down(localc, off, 64);
        if ((tid & 63) == 0) csum[tid >> 6] = localc;
    }
    __syncthreads();
    if (COUNT && tid == 0 && hs == 0) {
        float tot = csum[0] + csum[1] + csum[2] + csum[3];
        if (tot != 0.f) atomicAdd(cnt, tot);
    }
    int ks = tid >> 7, hh = tid & 127;
    float acc[8];
    #pragma unroll
    for (int b = 0; b < 8; ++b) acc[b] = 0.f;
    if (hh < 125) {
        int h = hs * 125 + hh;
        const float* Wp = W + (size_t)(j0 + ks * 20) * 1000 + h;
        const float4* abase = reinterpret_cast<const float4*>(&al[ks * 20 * 8]);
        #pragma unroll 4
        for (int jj = 0; jj < 20; ++jj) {
            float w = Wp[(size_t)jj * 1000];
            const float4* a4 = abase + jj * 2;
            #pragma unroll
            for (int q = 0; q < 2; ++q) {
                float4 av = a4[q];
                acc[q * 4 + 0] = fmaf(av.x, w, acc[q * 4 + 0]);
                acc[q * 4 + 1] = fmaf(av.y, w, acc[q * 4 + 1]);
                acc[q * 4 + 2] = fmaf(av.z, w, acc[q * 4 + 2]);
                acc[q * 4 + 3] = fmaf(av.w, w, acc[q * 4 + 3]);
            }
        }
    }
    if (ks == 1 && hh < 125) {
        #pragma unroll
        for (int b = 0; b < 8; ++b) redg[b * 128 + hh] = acc[b];
    }
    __syncthreads();
    if (ks == 0 && hh < 125) {
        int h = hs * 125 + hh;
        float* pp = pout + (size_t)kc * 32000 + (size_t)(bg * 8) * 1000 + h;
        #pragma unroll
        for (int b = 0; b < 8; ++b) pp[(size_t)b * 1000] = acc[b] + redg[b * 128 + hh];
    }
}

// dual-weight variant: layer-3 reduce+leaky(+count) staged, then K and V partials
__global__ __launch_bounds__(256) void k_gspred_kv(
    const float* __restrict__ pin, const float* __restrict__ bias,
    const float* __restrict__ mem_old, float* __restrict__ mem_new,
    const float* __restrict__ Wk, const float* __restrict__ Wv,
    float* __restrict__ pk, float* __restrict__ pv, float* cnt)
{
    int hs = blockIdx.x, kc = blockIdx.y, bg = blockIdx.z;
    int tid = threadIdx.x;
    int j0 = kc * 40;
    __shared__ __align__(16) float al[320];
    __shared__ float redk[8 * 128];
    __shared__ float redv[8 * 128];
    __shared__ float csum[4];
    float localc = 0.f;
    for (int e = tid; e < 320; e += 256) {
        int jj = e % 40, bi = e / 40;
        int idx = (bg * 8 + bi) * 1000 + j0 + jj;
        float a = bias[j0 + jj];
        #pragma unroll 5
        for (int c = 0; c < 25; ++c) a += pin[(size_t)c * 32000 + idx];
        float m = mem_old[idx];
        float r = (m - kTHR > 0.f) ? kTHR : 0.f;
        float mn = __fsub_rn(__fadd_rn(__fmul_rn(kBETA, m), a), r);
        float s = (mn - kTHR > 0.f) ? 1.f : 0.f;
        al[jj * 8 + bi] = s;
        if (hs == 0) { mem_new[idx] = mn; localc += s; }
    }
    for (int off = 32; off; off >>= 1) localc += __shfl_down(localc, off, 64);
    if ((tid & 63) == 0) csum[tid >> 6] = localc;
    __syncthreads();
    if (tid == 0 && hs == 0) {
        float tot = csum[0] + csum[1] + csum[2] + csum[3];
        if (tot != 0.f) atomicAdd(cnt, tot);
    }
    int ks = tid >> 7, hh = tid & 127;
    float ak[8], av2[8];
    #pragma unroll
    for (int b = 0; b < 8; ++b) { ak[b] = 0.f; av2[b] = 0.f; }
    if (hh < 125) {
        int h = hs * 125 + hh;
        const float* wkp = Wk + (size_t)(j0 + ks * 20) * 1000 + h;
        const float* wvp = Wv + (size_t)(j0 + ks * 20) * 1000 + h;
        const float4* abase = reinterpret_cast<const float4*>(&al[ks * 20 * 8]);
        #pragma unroll 4
        for (int jj = 0; jj < 20; ++jj) {
            float wk = wkp[(size_t)jj * 1000];
            float wv = wvp[(size_t)jj * 1000];
            const float4* a4 = abase + jj * 2;
            #pragma unroll
            for (int q = 0; q < 2; ++q) {
                float4 av = a4[q];
                ak[q * 4 + 0] = fmaf(av.x, wk, ak[q * 4 + 0]);
                ak[q * 4 + 1] = fmaf(av.y, wk, ak[q * 4 + 1]);
                ak[q * 4 + 2] = fmaf(av.z, wk, ak[q * 4 + 2]);
                ak[q * 4 + 3] = fmaf(av.w, wk, ak[q * 4 + 3]);
                av2[q * 4 + 0] = fmaf(av.x, wv, av2[q * 4 + 0]);
                av2[q * 4 + 1] = fmaf(av.y, wv, av2[q * 4 + 1]);
                av2[q * 4 + 2] = fmaf(av.z, wv, av2[q * 4 + 2]);
                av2[q * 4 + 3] = fmaf(av.w, wv, av2[q * 4 + 3]);
            }
        }
    }
    if (ks == 1 && hh < 125) {
        #pragma unroll
        for (int b = 0; b < 8; ++b) { redk[b * 128 + hh] = ak[b]; redv[b * 128 + hh] = av2[b]; }
    }
    __syncthreads();
    if (ks == 0 && hh < 125) {
        int h = hs * 125 + hh;
        float* ppk = pk + (size_t)kc * 32000 + (size_t)(bg * 8) * 1000 + h;
        float* ppv = pv + (size_t)kc * 32000 + (size_t)(bg * 8) * 1000 + h;
        #pragma unroll
        for (int b = 0; b < 8; ++b) {
            ppk[(size_t)b * 1000] = ak[b] + redk[b * 128 + hh];
            ppv[(size_t)b * 1000] = av2[b] + redv[b * 128 + hh];
        }
    }
}

// ---------------- attention: staged K/V reduce + fused q-GEMM + 2-way softmax + final ----------------
__global__ __launch_bounds__(256) void k_attnred(
    const float* __restrict__ pkk, const float* __restrict__ pvv,
    const float* __restrict__ bk, const float* __restrict__ bv,
    const float* __restrict__ spkr, const float* __restrict__ Wq,
    const float* __restrict__ bq, const float* __restrict__ Wo,
    const float* __restrict__ bo,
    float* __restrict__ patt, float* __restrict__ memo,
    float* __restrict__ oacc, const float* __restrict__ cnt,
    float* __restrict__ sc, float* __restrict__ dout,
    unsigned int* __restrict__ tick, int t)
{
    int it = blockIdx.x, b = blockIdx.y;
    int tid = threadIdx.x;
    __shared__ float kk[1000], vv[1000];
    __shared__ float sr[100];
    __shared__ float red[256];
    __shared__ float pden[256], pnum[256];
    __shared__ int isLast;
    float pmax = -3.4e38f, pmin = 3.4e38f;
    if (tid < 100) sr[tid] = spkr[b * 100 + tid];
    for (int h = tid; h < 1000; h += 256) {
        int idx = b * 1000 + h;
        float ak = bk[h], av = bv[h];
        #pragma unroll 5
        for (int c = 0; c < 25; ++c) {
            ak += pkk[(size_t)c * 32000 + idx];
            av += pvv[(size_t)c * 32000 + idx];
        }
        kk[h] = ak; vv[h] = av;
        pmax = fmaxf(pmax, ak);
        pmin = fminf(pmin, ak);
    }
    red[tid] = pmax;
    __syncthreads();
    for (int s2 = 128; s2 > 0; s2 >>= 1) {
        if (tid < s2) red[tid] = fmaxf(red[tid], red[tid + s2]);
        __syncthreads();
    }
    float kmax = red[0];
    __syncthreads();
    red[tid] = pmin;
    __syncthreads();
    for (int s2 = 128; s2 > 0; s2 >>= 1) {
        if (tid < s2) red[tid] = fminf(red[tid], red[tid + s2]);
        __syncthreads();
    }
    float kmin = red[0];
    __syncthreads();

    // 2-way split softmax: lane half computes 500-j partial num/den
    int half = tid >> 7, lane = tid & 127;
    float den = 0.f, num = 0.f;
    if (lane < 125) {
        int i = it * 125 + lane;
        float qi = bq[i];
        for (int j = 0; j < 100; ++j) qi = fmaf(sr[j], Wq[j * 1000 + i], qi);
        float qs = qi / 31.62277660168379f;   // sqrt(1000)
        float m = (qs >= 0.f) ? qs * kmax : qs * kmin;
        int jb = half * 500;
        for (int j = 0; j < 500; ++j) {
            float e = __expf(fmaf(qs, kk[jb + j], -m));
            den += e;
            num = fmaf(e, vv[jb + j], num);
        }
    }
    pden[tid] = den; pnum[tid] = num;
    __syncthreads();
    float pw = 0.f;
    if (tid < 125) {
        float dsum = pden[tid] + pden[tid + 128];
        float nsum = pnum[tid] + pnum[tid + 128];
        pw = (nsum / dsum) * Wo[it * 125 + tid];
    }
    red[tid] = (tid < 125) ? pw : 0.f;
    __syncthreads();
    for (int s2 = 128; s2 > 0; s2 >>= 1) {
        if (tid < s2) red[tid] += red[tid + s2];
        __syncthreads();
    }
    if (tid == 0) patt[b * 8 + it] = red[0];
    __syncthreads();
    if (tid == 0) {
        __threadfence();
        unsigned r = atomicAdd(tick, 1u);
        isLast = (r == 255u) ? 1 : 0;
    }
    __syncthreads();
    if (isLast && tid < 64) {
        __threadfence();
        float s = 0.f;
        if (tid < 32) {
            float a = bo[0];
            for (int itx = 0; itx < 8; ++itx) a += patt[tid * 8 + itx];
            float m = memo[tid];
            float r = (m - kTHR > 0.f) ? kTHR : 0.f;
            float mn = __fsub_rn(__fadd_rn(__fmul_rn(kBETA, m), a), r);
            memo[tid] = mn;
            s = (mn - kTHR > 0.f) ? 1.f : 0.f;
            float oa = oacc[tid] + s;
            oacc[tid] = oa;
            if (t == 4) dout[tid] = oa / 5.0f;
        }
        unsigned long long msk = __ballot(s > 0.5f);
        float co = (float)__popcll(msk);
        if (tid == 0) {
            float total = sc[0];
            float prev = total;
            total = __fadd_rn(total, __fdiv_rn(cnt[0], 32000.f));
            total = __fadd_rn(total, __fdiv_rn(cnt[1], 32000.f));
            total = __fadd_rn(total, __fdiv_rn(cnt[2], 3200.f));
            total = __fadd_rn(total, __fdiv_rn(co, 32.f));
            float reg = sc[1];
            reg = __fadd_rn(reg, __fmul_rn(kLM, total));
            if (t > 0) reg = __fadd_rn(reg, __fmul_rn(kLM, fabsf(__fsub_rn(total, prev))));
            sc[0] = total; sc[1] = reg;
            if (t == 4) dout[32] = reg / 5.0f;
        }
    }
}

// ---------------- host ----------------
extern "C" void kernel_launch(void* const* d_in, const int* in_sizes, int n_in,
                              void* d_out, int out_size, void* d_ws, size_t ws_size,
                              hipStream_t stream)
{
    const float* data = (const float*)d_in[0];
    const float* Wpe  = (const float*)d_in[1];
    const float* bpe  = (const float*)d_in[2];
    const float* pos  = (const float*)d_in[3];
    const float* W1   = (const float*)d_in[4];
    const float* b1   = (const float*)d_in[5];
    const float* W2   = (const float*)d_in[6];
    const float* b2   = (const float*)d_in[7];
    const float* W3   = (const float*)d_in[8];
    const float* b3   = (const float*)d_in[9];
    const float* WR   = (const float*)d_in[10];
    const float* bR   = (const float*)d_in[11];
    const float* Vw   = (const float*)d_in[12];
    const float* Vb   = (const float*)d_in[13];
    const float* Wq   = (const float*)d_in[14];
    const float* bq   = (const float*)d_in[15];
    const float* Wk   = (const float*)d_in[16];
    const float* bk   = (const float*)d_in[17];
    const float* Wv   = (const float*)d_in[18];
    const float* bv   = (const float*)d_in[19];
    const float* Wo   = (const float*)d_in[20];
    const float* bo   = (const float*)d_in[21];

    float* ws = (float*)d_ws;
    float* dout = (float*)d_out;

    float* xf    = ws + OFF_X;
    float* cur1  = ws + OFF_CUR1;
    float* mem1  = ws + OFF_MEM1;
    float* mem2a = ws + OFF_MEM2;
    float* mem3a = ws + OFF_MEM3;
    float* spk1b = ws + OFF_SPK1B;
    float* memr  = ws + OFF_MEMR;
    float* spkr  = ws + OFF_SPKR;
    float* memo  = ws + OFF_MEMO;
    float* patt  = ws + OFF_PATT;
    float* cntb  = ws + OFF_CNT;
    float* oacc  = ws + OFF_OACC;
    float* sc    = ws + OFF_SC;
    unsigned int* tick = (unsigned int*)(ws + OFF_TICK);
    float* part  = ws + OFF_PART;
    float* pg2   = ws + OFF_PG2;
    float* pg3   = ws + OFF_PG3;
    float* pkk   = ws + OFF_PKK;
    float* pvv   = ws + OFF_PVV;
    float* mem2b = ws + OFF_M2B;
    float* mem3b = ws + OFF_M3B;

    // chunk count for the big GEMM: cap 365 (tpc=2) -> 730 blocks, 46.7 MB partials
    size_t ws_f = ws_size / 4;
    size_t avail = (ws_f > OFF_PART) ? (ws_f - OFF_PART) : 0;
    long nchunk_l = (long)(avail / 32000);
    int nchunk = (nchunk_l > 365) ? 365 : (int)nchunk_l;
    if (nchunk < 1) nchunk = 1;
    int tpc = (729 + nchunk - 1) / nchunk;
    nchunk = (729 + tpc - 1) / tpc;

    k_init<<<402, 256, 0, stream>>>(ws);
    k_patch<<<dim3(32, 27), 64, 0, stream>>>(data, Wpe, bpe, pos, xf);
    k_gemm1_part<<<dim3(nchunk, 2), 256, 0, stream>>>(xf, W1, part, tpc);
    k_gemm1_reduce<<<250, 128, 0, stream>>>(part, b1, cur1, nchunk);

    for (int t = 0; t < 5; ++t) {
        float* cnt = cntb + t * 4;
        float* m2o = (t & 1) ? mem2b : mem2a;
        float* m2n = (t & 1) ? mem2a : mem2b;
        float* m3o = (t & 1) ? mem3b : mem3a;
        float* m3n = (t & 1) ? mem3a : mem3b;

        // 1. double-leaky + RLeaky (512 thr, 4-way WR split)
        k_stepR<<<32, 512, 0, stream>>>(cur1, mem1, spk1b, WR, bR, Vw, Vb,
                                        memr, spkr, cnt + 0, cnt + 2);
        // 2. layer-2 GEMM partials: spk1b @ W2 -> pg2
        k_gsp<<<dim3(8, 25, 4), 256, 0, stream>>>(spk1b, W2, pg2);
        // 3. reduce pg2 + leaky(mem2) staged, GEMM @ W3 -> pg3
        k_gspred<false><<<dim3(8, 25, 4), 256, 0, stream>>>(
            pg2, b2, m2o, m2n, W3, pg3, nullptr);
        // 4. reduce pg3 + leaky(mem3)(+count) staged, GEMM @ Wk/Wv -> pkk, pvv
        k_gspred_kv<<<dim3(8, 25, 4), 256, 0, stream>>>(
            pg3, b3, m3o, m3n, Wk, Wv, pkk, pvv, cnt + 1);
        // 5. attention: reduce K/V + fused q + 2-way softmax + last-block final
        k_attnred<<<dim3(8, 32), 256, 0, stream>>>(
            pkk, pvv, bk, bv, spkr, Wq, bq, Wo, bo,
            patt, memo, oacc, cnt, sc, dout, tick + t, t);
    }
    (void)in_sizes; (void)n_in; (void)out_size;
}